// Round 12
// baseline (256.513 us; speedup 1.0000x reference)
//
#include <hip/hip_runtime.h>
#include <hip/hip_bf16.h>

#define T_TRIP 500000
#define NP     100000
#define NPAD   500032
#define NBATCH 31252   // NPAD/16

typedef float f32x4 __attribute__((ext_vector_type(4)));
typedef __bf16 bf16x8 __attribute__((ext_vector_type(8)));
typedef unsigned short u16;
typedef unsigned short u16x8 __attribute__((ext_vector_type(8)));
typedef unsigned int u32;

__device__ __forceinline__ u16 f2bf(float f) {
  union { float f; unsigned u; } v; v.f = f;
  unsigned r = v.u + 0x7fffu + ((v.u >> 16) & 1u);
  return (u16)(r >> 16);
}

__device__ __forceinline__ ushort4 cvt4(float4 v) {
  ushort4 o; o.x = f2bf(v.x); o.y = f2bf(v.y); o.z = f2bf(v.z); o.w = f2bf(v.w);
  return o;
}

__device__ __forceinline__ u16 cvt1_pk(float v) {
  unsigned r;
  asm("v_cvt_pk_bf16_f32 %0, %1, %1" : "=v"(r) : "v"(v));
  return (u16)r;
}

__device__ __forceinline__ float bflo(u32 d) {
  union { u32 u; float f; } v; v.u = d << 16; return v.f;
}
__device__ __forceinline__ float bfhi(u32 d) {
  union { u32 u; float f; } v; v.u = d & 0xffff0000u; return v.f;
}

#define MFMA16(a, b, c) __builtin_amdgcn_mfma_f32_16x16x32_bf16((a), (b), (c), 0, 0, 0)
#define LGKM0()   asm volatile("s_waitcnt lgkmcnt(0)" ::: "memory")

// =================== ws layout ===================
#define FP_W1A   0u
#define FP_W1B   16384u
#define FP_W1C   32768u
#define FP_W2    49152u     // PERMUTED K layout (pi)
#define FP_PW1   65536u
#define FP_PW2   98304u
#define FP_W1D   114688u    // f32 [4][128]
#define FP_H     131072u    // h_pair bf16 [NP][128]
#define FP_AGG   12931072u  // Hagg bf16 [NP][128] (PERMUTED col layout)
#define SB_CNT2    51462144ull
#define SB_CURSOR2 51862144ull
#define SB_BSUM2   52262144ull
#define SB_TRIP    52262656ull          // 16B packed AoS per triplet
#define SB_YA      60263168ull          // u32 [NP][64] dword q <-> cols (c0(q), c0(q)+16)
#define SB_YB      85863168ull
#define SB_YC     111463168ull
#define WS_S3     137063168ull

#define HSTR   136
#define X2STR  264

// permuted-K map: u16 position i <-> column pi(i)
// pi(i) = ((i>>5)<<5) + ((i>>1)&15) + ((i&1)<<4)   [q=i>>1: c0(q)=(q>>4)*32+(q&15)]
__device__ __host__ __forceinline__ int pi_col(int i) {
  int q = i >> 1;
  return ((q >> 4) << 5) + (q & 15) + ((i & 1) << 4);
}

// ---------------- pre: weights prep + zero Hagg + histogram ----------------
__global__ void k_pre3(const float* __restrict__ psi_w1, const float* __restrict__ psi_w2,
                       const float* __restrict__ phi_w1, const float* __restrict__ phi_w2,
                       const int* __restrict__ ivw,
                       u16* __restrict__ ws, int* __restrict__ cnt) {
  const int b = blockIdx.x;
  if (b < 450) {
    int i = b * 256 + threadIdx.x;
    if (i < 49152) {
      int s = i / 16384, r = i % 16384;
      int n = r / 128, k = r % 128;
      ws[FP_W1A + i] = f2bf(psi_w1[(s * 128 + k) * 128 + n]);
      return;
    }
    i -= 49152;
    if (i < 16384) {                       // W2T with K permuted by pi
      int n = i / 128, k = i % 128;
      ws[FP_W2 + i] = f2bf(psi_w2[pi_col(k) * 128 + n]);
      return;
    }
    i -= 16384;
    if (i < 32768) {
      int n = i / 256, k = i % 256;
      ws[FP_PW1 + i] = f2bf(phi_w1[k * 128 + n]);
      return;
    }
    i -= 32768;
    if (i < 16384) {
      int n = i / 128, k = i % 128;
      ws[FP_PW2 + i] = f2bf(phi_w2[k * 128 + n]);
      return;
    }
    i -= 16384;
    if (i < 512) {
      int k = i / 128, n = i % 128;
      reinterpret_cast<float*>(ws + FP_W1D)[i] = psi_w1[(384 + k) * 128 + n];
    }
  } else if (b < 3575) {
    const size_t i = (size_t)((b - 450) * 256 + threadIdx.x) * 16;
    ushort4 z = {0, 0, 0, 0};
    u16* d = ws + FP_AGG + i;
#pragma unroll
    for (int k = 0; k < 4; ++k) *reinterpret_cast<ushort4*>(d + k * 4) = z;
  } else {
    int i = (b - 3575) * 256 + threadIdx.x;
    if (i < T_TRIP) atomicAdd(&cnt[ivw[i]], 1);
  }
}

// ================= scan =================
__global__ __launch_bounds__(1024) void k_scan1(const int* __restrict__ cnt,
                                                int* __restrict__ cursor, int* __restrict__ bsum) {
  __shared__ int wsum[16];
  const int idx = blockIdx.x * 1024 + threadIdx.x;
  const int lane = threadIdx.x & 63, wid = threadIdx.x >> 6;
  int v = (idx < NP) ? cnt[idx] : 0;
  int x = v;
#pragma unroll
  for (int off = 1; off < 64; off <<= 1) {
    int n = __shfl_up(x, off);
    if (lane >= off) x += n;
  }
  if (lane == 63) wsum[wid] = x;
  __syncthreads();
  if (threadIdx.x < 16) {
    int s = wsum[threadIdx.x];
#pragma unroll
    for (int off = 1; off < 16; off <<= 1) {
      int n = __shfl_up(s, off);
      if (threadIdx.x >= off) s += n;
    }
    wsum[threadIdx.x] = s;
  }
  __syncthreads();
  const int base = wid ? wsum[wid - 1] : 0;
  if (idx < NP) cursor[idx] = base + x - v;
  if (threadIdx.x == 1023) bsum[blockIdx.x] = base + x;
}

__global__ void k_scan2(int* __restrict__ bsum) {
  __shared__ int s[128];
  const int t = threadIdx.x;
  int v = (t < 98) ? bsum[t] : 0;
  s[t] = v; __syncthreads();
#pragma unroll
  for (int off = 1; off < 128; off <<= 1) {
    int a = (t >= off) ? s[t - off] : 0;
    __syncthreads();
    s[t] += a;
    __syncthreads();
  }
  if (t < 98) bsum[t] = s[t] - v;
}

// ================= permute -> 16B packed AoS =================
__global__ void k_perm_pack(const int* __restrict__ ivu, const int* __restrict__ iuw,
                            const int* __restrict__ ivw, const float* __restrict__ geom,
                            int* __restrict__ cursor, const int* __restrict__ bsum,
                            int4* __restrict__ trip) {
  int i = blockIdx.x * 256 + threadIdx.x;
  if (i < T_TRIP) {
    int v = ivw[i];
    int pos = atomicAdd(&cursor[v], 1) + bsum[v >> 10];
    float4 g = reinterpret_cast<const float4*>(geom)[i];
    u32 pk0, pk1;
    asm("v_cvt_pk_bf16_f32 %0, %1, %2" : "=v"(pk0) : "v"(g.x), "v"(g.y));
    asm("v_cvt_pk_bf16_f32 %0, %1, %2" : "=v"(pk1) : "v"(g.z), "v"(g.w));
    int4 rec;
    rec.x = ivu[i] | ((v & 0x7fff) << 17);
    rec.y = iuw[i] | ((v >> 15) << 17);
    rec.z = (int)pk0;
    rec.w = (int)pk1;
    trip[pos] = rec;
  } else if (i < NPAD) {
    int4 z = {0, 0, 0, 0};
    trip[i] = z;
  }
}

// ================= proj: h -> H bf16, Y_{a,b,c} = H @ W1{a,b,c}^T =================
// Permuted Y dword layout: dword q of a row = pk(col c0(q), col c0(q)+16).
// Epilogue is pure in-lane cvt_pk + store (no shuffles).
__global__ __launch_bounds__(256, 4) void k_proj(
    const float* __restrict__ h, const u16* __restrict__ W1A, const u16* __restrict__ W1B,
    const u16* __restrict__ W1C, u16* __restrict__ H,
    u32* __restrict__ YA, u32* __restrict__ YB, u32* __restrict__ YC) {
  __shared__ __align__(16) u16 xs[64 * 132];
  const int tid = threadIdx.x;
  const int r0 = blockIdx.x * 64;
  {
    const int row = tid >> 2, q = tid & 3;
    int rc = r0 + row; rc = (rc < NP) ? rc : (NP - 1);
    const float4* src = reinterpret_cast<const float4*>(h + (size_t)rc * 128 + q * 32);
    u16* ldst = &xs[row * 132 + q * 32];
    u16* gdst = H + (size_t)rc * 128 + q * 32;
#pragma unroll
    for (int i = 0; i < 8; ++i) {
      ushort4 c = cvt4(src[i]);
      *reinterpret_cast<ushort4*>(ldst + i * 4) = c;
      *reinterpret_cast<ushort4*>(gdst + i * 4) = c;
    }
  }
  __syncthreads();
  const int w = tid >> 6, l = tid & 63;
  const int lr = l & 15, lk = (l >> 4) << 3;
  const int n0 = w * 32 + lr;
  const int rowh = (l >> 4) << 2;
  const int qd = w * 16 + lr;                  // Y dword index: c0(qd) == n0

  const u16* WT[3] = {W1A, W1B, W1C};
  u32* YT[3] = {YA, YB, YC};
#pragma unroll
  for (int s = 0; s < 3; ++s) {
    f32x4 acc[4][2] = {};
#pragma unroll
    for (int ks = 0; ks < 4; ++ks) {
      bf16x8 a[4], b[2];
#pragma unroll
      for (int rt = 0; rt < 4; ++rt)
        a[rt] = *reinterpret_cast<const bf16x8*>(&xs[(rt * 16 + lr) * 132 + ks * 32 + lk]);
#pragma unroll
      for (int ct = 0; ct < 2; ++ct)
        b[ct] = *reinterpret_cast<const bf16x8*>(&WT[s][(size_t)(n0 + ct * 16) * 128 + ks * 32 + lk]);
#pragma unroll
      for (int rt = 0; rt < 4; ++rt)
#pragma unroll
        for (int ct = 0; ct < 2; ++ct)
          acc[rt][ct] = MFMA16(a[rt], b[ct], acc[rt][ct]);
    }
#pragma unroll
    for (int rt = 0; rt < 4; ++rt)
#pragma unroll
      for (int j = 0; j < 4; ++j) {
        const int row = rt * 16 + rowh + j;
        if (r0 + row < NP) {
          u32 pk;
          asm("v_cvt_pk_bf16_f32 %0, %1, %2" : "=v"(pk) : "v"(acc[rt][0][j]), "v"(acc[rt][1][j]));
          YT[s][(size_t)(r0 + row) * 64 + qd] = pk;
        }
      }
  }
}

// ================= gsilu2: gather + silu + run-reduce; plain stores for interior runs =================
// Lane l handles cols c0 = (l>>4)*32 + (l&15) and c0+16 (permuted layout).
__global__ void k_gsilu2(
    const u32* __restrict__ YA, const u32* __restrict__ YB, const u32* __restrict__ YC,
    const u32* __restrict__ tripw, const float* __restrict__ w1dF,
    const float* __restrict__ b1, u16* __restrict__ Hagg) {
  const int w = threadIdx.x >> 6, l = threadIdx.x & 63;
  const int batch = blockIdx.x * 4 + w;
  if (batch >= NBATCH) return;
  const int t0 = batch * 16;
  const int c0 = ((l >> 4) << 5) + (l & 15);

  const u32 aos = tripw[(size_t)batch * 64 + l];

  float wd[4][2];
#pragma unroll
  for (int k = 0; k < 4; ++k) {
    wd[k][0] = w1dF[k * 128 + c0];
    wd[k][1] = w1dF[k * 128 + c0 + 16];
  }
  const float bb0 = b1[c0], bb1 = b1[c0 + 16];

  int vw[16];
  u32 g2[16], g3[16], ga[16], gb[16];
#pragma unroll
  for (int i = 0; i < 16; ++i) {
    const u32 d0 = (u32)__shfl((int)aos, i * 4);
    const u32 d1 = (u32)__shfl((int)aos, i * 4 + 1);
    g2[i] = (u32)__shfl((int)aos, i * 4 + 2);
    g3[i] = (u32)__shfl((int)aos, i * 4 + 3);
    vw[i] = (int)((d0 >> 17) | ((d1 >> 17) << 15));
    ga[i] = YA[(size_t)(d0 & 0x1FFFF) * 64 + l];
    gb[i] = YB[(size_t)(d1 & 0x1FFFF) * 64 + l];
  }

  int prevVw = -1, nextVw = -1;
  if (t0 > 0) {
    u32 pd0 = tripw[(size_t)(t0 - 1) * 4];
    u32 pd1 = tripw[(size_t)(t0 - 1) * 4 + 1];
    prevVw = (int)((pd0 >> 17) | ((pd1 >> 17) << 15));
  }
  if (t0 + 16 < T_TRIP) {
    u32 nd0 = tripw[(size_t)(t0 + 16) * 4];
    u32 nd1 = tripw[(size_t)(t0 + 16) * 4 + 1];
    nextVw = (int)((nd0 >> 17) | ((nd1 >> 17) << 15));
  }

  float lo = 0.f, hi = 0.f;
  u32 gcc = 0;
  int istart = 0;
#pragma unroll
  for (int i = 0; i < 16; ++i) {
    const bool runStart = (i == 0) || (vw[i] != vw[i - 1]);
    if (runStart) {
      istart = i;
      gcc = YC[(size_t)vw[i] * 64 + l];
    }
    if (t0 + i < T_TRIP) {
      const float gx = bflo(g2[i]), gy = bfhi(g2[i]), gz = bflo(g3[i]), gw4 = bfhi(g3[i]);
      float p0 = bflo(ga[i]) + bflo(gb[i]) + bflo(gcc) + bb0
               + gx * wd[0][0] + gy * wd[1][0] + gz * wd[2][0] + gw4 * wd[3][0];
      float p1 = bfhi(ga[i]) + bfhi(gb[i]) + bfhi(gcc) + bb1
               + gx * wd[0][1] + gy * wd[1][1] + gz * wd[2][1] + gw4 * wd[3][1];
      lo += p0 * __builtin_amdgcn_rcpf(1.f + __expf(-p0));
      hi += p1 * __builtin_amdgcn_rcpf(1.f + __expf(-p1));
    }
    bool doflush;
    if (i == 15) doflush = true;
    else doflush = (vw[i + 1] != vw[i]);
    if (doflush && (t0 + istart < T_TRIP)) {
      const bool contL = (istart == 0) && (vw[i] == prevVw);
      const bool contR = (i == 15) && (vw[i] == nextVw);
      u16* p = Hagg + (size_t)vw[i] * 128 + l * 2;   // permuted position, matches W2T pi
      u32 pk;
      asm("v_cvt_pk_bf16_f32 %0, %1, %2" : "=v"(pk) : "v"(lo), "v"(hi));
      if (contL || contR) {
        asm volatile("global_atomic_pk_add_bf16 %0, %1, off" :: "v"(p), "v"(pk) : "memory");
      } else {
        *reinterpret_cast<u32*>(p) = pk;
      }
      lo = 0.f; hi = 0.f;
    }
  }
}

// ================= pair2: agg = Hagg@W2 + cnt*b2; out = h + phi([H|agg]) =================
// Hagg is col-permuted; W2T was stored with matching K permutation -> GEMM exact.
__global__ __launch_bounds__(256, 3) void k_pair2(
    const float* __restrict__ h_pair, const u16* __restrict__ H, const u16* __restrict__ Hagg,
    const int* __restrict__ cnt, const u16* __restrict__ W2T,
    const u16* __restrict__ PW1T, const u16* __restrict__ PW2T,
    const float* __restrict__ psi_b2, const float* __restrict__ b1, const float* __restrict__ b2,
    float* __restrict__ out) {
  __shared__ __align__(16) u16 xl[64 * X2STR];
  __shared__ __align__(16) u16 hl[64 * HSTR];
  u32* xl32 = reinterpret_cast<u32*>(xl);

  const int tid = threadIdx.x;
  const int r0 = blockIdx.x * 64;

  {
    const int row = tid >> 2, q = tid & 3;
    int rc = r0 + row; rc = (rc < NP) ? rc : (NP - 1);
    const u16x8* sh = reinterpret_cast<const u16x8*>(H + (size_t)rc * 128 + q * 32);
    const u16x8* sa = reinterpret_cast<const u16x8*>(Hagg + (size_t)rc * 128 + q * 32);
    u16x8* d1 = reinterpret_cast<u16x8*>(&xl[row * X2STR + q * 32]);
    u16x8* d2 = reinterpret_cast<u16x8*>(&hl[row * HSTR + q * 32]);
#pragma unroll
    for (int i = 0; i < 4; ++i) { d1[i] = sh[i]; d2[i] = sa[i]; }
  }
  __syncthreads();

  const int w = tid >> 6, l = tid & 63;
  const int lr = l & 15, lk = (l >> 4) << 3;
  const int n0 = w * 32 + lr;
  const int rowh = (l >> 4) << 2;

  // ---- front GEMM: agg = Hagg_perm @ W2T_perm + cnt*psi_b2 -> xl cols 128..255 ----
  {
    f32x4 acc[4][2] = {};
#pragma unroll
    for (int ks = 0; ks < 4; ++ks) {
      bf16x8 a[4], b[2];
#pragma unroll
      for (int rt = 0; rt < 4; ++rt)
        a[rt] = *reinterpret_cast<const bf16x8*>(&hl[(rt * 16 + lr) * HSTR + ks * 32 + lk]);
#pragma unroll
      for (int ct = 0; ct < 2; ++ct)
        b[ct] = *reinterpret_cast<const bf16x8*>(&W2T[(size_t)(n0 + ct * 16) * 128 + ks * 32 + lk]);
#pragma unroll
      for (int rt = 0; rt < 4; ++rt)
#pragma unroll
        for (int ct = 0; ct < 2; ++ct)
          acc[rt][ct] = MFMA16(a[rt], b[ct], acc[rt][ct]);
    }
    const float pb2v[2] = {psi_b2[n0], psi_b2[n0 + 16]};
#pragma unroll
    for (int rt = 0; rt < 4; ++rt)
#pragma unroll
      for (int j = 0; j < 4; ++j) {
        const int row = rt * 16 + rowh + j;
        int rc = r0 + row; rc = (rc < NP) ? rc : (NP - 1);
        const float cf = (float)cnt[rc];
        float v0 = acc[rt][0][j] + cf * pb2v[0];
        float v1 = acc[rt][1][j] + cf * pb2v[1];
        float x0 = __shfl_xor(v0, 1), x1 = __shfl_xor(v1, 1);
        const bool even = (l & 1) == 0;
        float lo = even ? v0 : x1, hi = even ? x0 : v1;
        const int dcol = even ? (n0 >> 1) : ((n0 + 15) >> 1);
        u32 pk;
        asm("v_cvt_pk_bf16_f32 %0, %1, %2" : "=v"(pk) : "v"(lo), "v"(hi));
        xl32[row * (X2STR / 2) + 64 + dcol] = pk;
      }
  }
  LGKM0();
  __syncthreads();

  // ---- phi GEMM1 (K=256) ----
  f32x4 acc[4][2] = {};
#pragma unroll 1
  for (int ks = 0; ks < 8; ++ks) {
    const int k0 = ks * 32;
    bf16x8 a[4], b[2];
#pragma unroll
    for (int rt = 0; rt < 4; ++rt)
      a[rt] = *reinterpret_cast<const bf16x8*>(&xl[(rt * 16 + lr) * X2STR + k0 + lk]);
#pragma unroll
    for (int ct = 0; ct < 2; ++ct)
      b[ct] = *reinterpret_cast<const bf16x8*>(&PW1T[(size_t)(n0 + ct * 16) * 256 + k0 + lk]);
#pragma unroll
    for (int rt = 0; rt < 4; ++rt)
#pragma unroll
      for (int ct = 0; ct < 2; ++ct)
        acc[rt][ct] = MFMA16(a[rt], b[ct], acc[rt][ct]);
  }

  {
    const float b1v0 = b1[n0], b1v1 = b1[n0 + 16];
#pragma unroll
    for (int rt = 0; rt < 4; ++rt)
#pragma unroll
      for (int ct = 0; ct < 2; ++ct) {
        const float bb = ct ? b1v1 : b1v0;
#pragma unroll
        for (int j = 0; j < 4; ++j) {
          float v = acc[rt][ct][j] + bb;
          v = v * __builtin_amdgcn_rcpf(1.f + __expf(-v));
          hl[(rt * 16 + rowh + j) * HSTR + n0 + ct * 16] = cvt1_pk(v);
        }
      }
  }
  __syncthreads();

  // ---- phi GEMM2 ----
  f32x4 acc2[4][2] = {};
#pragma unroll
  for (int ks = 0; ks < 4; ++ks) {
    const int k0 = ks * 32;
    bf16x8 a[4], b[2];
#pragma unroll
    for (int rt = 0; rt < 4; ++rt)
      a[rt] = *reinterpret_cast<const bf16x8*>(&hl[(rt * 16 + lr) * HSTR + k0 + lk]);
#pragma unroll
    for (int ct = 0; ct < 2; ++ct)
      b[ct] = *reinterpret_cast<const bf16x8*>(&PW2T[(size_t)(n0 + ct * 16) * 128 + k0 + lk]);
#pragma unroll
    for (int rt = 0; rt < 4; ++rt)
#pragma unroll
      for (int ct = 0; ct < 2; ++ct)
        acc2[rt][ct] = MFMA16(a[rt], b[ct], acc2[rt][ct]);
  }

  {
    const float b2v0 = b2[n0], b2v1 = b2[n0 + 16];
#pragma unroll
    for (int rt = 0; rt < 4; ++rt)
#pragma unroll
      for (int j = 0; j < 4; ++j) {
        const int row = rt * 16 + rowh + j;
        const int r = r0 + row;
        if (r < NP) {
          out[(size_t)r * 128 + n0]      = h_pair[(size_t)r * 128 + n0]      + acc2[rt][0][j] + b2v0;
          out[(size_t)r * 128 + n0 + 16] = h_pair[(size_t)r * 128 + n0 + 16] + acc2[rt][1][j] + b2v1;
        }
      }
  }
}

// ===================== R0 fallback (tiny ws) =====================
#define PSI_W1T_OFF 0
#define PSI_W2T_OFF 53248
#define PHI_W1T_OFF 69632
#define PHI_W2T_OFF 102400
#define WS_U16_TOTAL 118784
#define XSTR 424

__global__ void k_prep(const float* __restrict__ psi_w1, const float* __restrict__ psi_w2,
                       const float* __restrict__ phi_w1, const float* __restrict__ phi_w2,
                       u16* __restrict__ ws) {
  int i = blockIdx.x * 256 + threadIdx.x;
  if (i < 128 * 416) {
    int n = i / 416, k = i % 416;
    ws[PSI_W1T_OFF + i] = f2bf(k < 388 ? psi_w1[k * 128 + n] : 0.f);
    return;
  }
  i -= 128 * 416;
  if (i < 128 * 128) {
    int n = i / 128, k = i % 128;
    ws[PSI_W2T_OFF + i] = f2bf(psi_w2[k * 128 + n]);
    return;
  }
  i -= 128 * 128;
  if (i < 128 * 256) {
    int n = i / 256, k = i % 256;
    ws[PHI_W1T_OFF + i] = f2bf(phi_w1[k * 128 + n]);
    return;
  }
  i -= 128 * 256;
  if (i < 128 * 128) {
    int n = i / 128, k = i % 128;
    ws[PHI_W2T_OFF + i] = f2bf(phi_w2[k * 128 + n]);
  }
}

__global__ __launch_bounds__(256, 2) void k_triplet(
    const float* __restrict__ h_pair,
    const int* __restrict__ ivu, const int* __restrict__ iuw, const int* __restrict__ ivw,
    const float* __restrict__ geom,
    const u16* __restrict__ W1T, const u16* __restrict__ W2T,
    const float* __restrict__ b1, const float* __restrict__ b2,
    float* __restrict__ agg) {
  __shared__ __align__(16) u16 xl[64 * XSTR];
  __shared__ __align__(16) u16 hl[64 * HSTR];
  __shared__ int svw[64];

  const int tid = threadIdx.x;
  const int t0 = blockIdx.x * 64;

  {
    const int row = tid >> 2, q = tid & 3;
    const int t = t0 + row;
    const int tc = (t < T_TRIP) ? t : (T_TRIP - 1);
    if (q == 0) svw[row] = (t < T_TRIP) ? ivw[tc] : -1;
    int idx[3];
    idx[0] = ivu[tc]; idx[1] = iuw[tc]; idx[2] = ivw[tc];
#pragma unroll
    for (int s = 0; s < 3; ++s) {
      const float4* src = reinterpret_cast<const float4*>(h_pair + (size_t)idx[s] * 128 + q * 32);
      u16* dst = &xl[row * XSTR + s * 128 + q * 32];
#pragma unroll
      for (int i = 0; i < 8; ++i)
        *reinterpret_cast<ushort4*>(dst + i * 4) = cvt4(src[i]);
    }
  }
  if (tid < 64) {
    const int t = t0 + tid;
    const int tc = (t < T_TRIP) ? t : (T_TRIP - 1);
    const float4 g = reinterpret_cast<const float4*>(geom)[tc];
    u16* dst = &xl[tid * XSTR + 384];
    *reinterpret_cast<ushort4*>(dst) = cvt4(g);
    ushort4 z = {0, 0, 0, 0};
#pragma unroll
    for (int i = 1; i < 8; ++i) *reinterpret_cast<ushort4*>(dst + i * 4) = z;
  }
  __syncthreads();

  const int w = tid >> 6;
  const int l = tid & 63;
  const int lr = l & 15;
  const int lk = (l >> 4) << 3;
  const int n0 = w * 32 + lr;
  const int rowh = (l >> 4) << 2;

  f32x4 acc[4][2] = {};
#pragma unroll 1
  for (int ks = 0; ks < 13; ++ks) {
    const int k0 = ks * 32;
    bf16x8 a[4], b[2];
#pragma unroll
    for (int rt = 0; rt < 4; ++rt)
      a[rt] = *reinterpret_cast<const bf16x8*>(&xl[(rt * 16 + lr) * XSTR + k0 + lk]);
#pragma unroll
    for (int ct = 0; ct < 2; ++ct)
      b[ct] = *reinterpret_cast<const bf16x8*>(&W1T[(size_t)(n0 + ct * 16) * 416 + k0 + lk]);
#pragma unroll
    for (int rt = 0; rt < 4; ++rt)
#pragma unroll
      for (int ct = 0; ct < 2; ++ct)
        acc[rt][ct] = MFMA16(a[rt], b[ct], acc[rt][ct]);
  }

  {
    const float b1v0 = b1[n0], b1v1 = b1[n0 + 16];
#pragma unroll
    for (int rt = 0; rt < 4; ++rt)
#pragma unroll
      for (int ct = 0; ct < 2; ++ct) {
        const float bb = ct ? b1v1 : b1v0;
#pragma unroll
        for (int j = 0; j < 4; ++j) {
          float v = acc[rt][ct][j] + bb;
          v = v / (1.f + __expf(-v));
          hl[(rt * 16 + rowh + j) * HSTR + n0 + ct * 16] = f2bf(v);
        }
      }
  }
  __syncthreads();

  f32x4 acc2[4][2] = {};
#pragma unroll
  for (int ks = 0; ks < 4; ++ks) {
    const int k0 = ks * 32;
    bf16x8 a[4], b[2];
#pragma unroll
    for (int rt = 0; rt < 4; ++rt)
      a[rt] = *reinterpret_cast<const bf16x8*>(&hl[(rt * 16 + lr) * HSTR + k0 + lk]);
#pragma unroll
    for (int ct = 0; ct < 2; ++ct)
      b[ct] = *reinterpret_cast<const bf16x8*>(&W2T[(size_t)(n0 + ct * 16) * 128 + k0 + lk]);
#pragma unroll
    for (int rt = 0; rt < 4; ++rt)
#pragma unroll
      for (int ct = 0; ct < 2; ++ct)
        acc2[rt][ct] = MFMA16(a[rt], b[ct], acc2[rt][ct]);
  }

  {
    const float b2v0 = b2[n0], b2v1 = b2[n0 + 16];
#pragma unroll
    for (int rt = 0; rt < 4; ++rt)
#pragma unroll
      for (int j = 0; j < 4; ++j) {
        const int row = rt * 16 + rowh + j;
        const int dst = svw[row];
        if (dst >= 0) {
          unsafeAtomicAdd(&agg[(size_t)dst * 128 + n0], acc2[rt][0][j] + b2v0);
          unsafeAtomicAdd(&agg[(size_t)dst * 128 + n0 + 16], acc2[rt][1][j] + b2v1);
        }
      }
  }
}

__global__ __launch_bounds__(256, 2) void k_pair(
    const float* __restrict__ h_pair,
    const u16* __restrict__ W1T, const u16* __restrict__ W2T,
    const float* __restrict__ b1, const float* __restrict__ b2,
    float* __restrict__ out) {
  __shared__ __align__(16) u16 xl[64 * X2STR];
  __shared__ __align__(16) u16 hl[64 * HSTR];

  const int tid = threadIdx.x;
  const int r0 = blockIdx.x * 64;

  {
    const int row = tid >> 2, q = tid & 3;
    const int r = r0 + row;
    const int rc = (r < NP) ? r : (NP - 1);
    const float4* s1 = reinterpret_cast<const float4*>(h_pair + (size_t)rc * 128 + q * 32);
    const float4* s2 = reinterpret_cast<const float4*>(out + (size_t)rc * 128 + q * 32);
    u16* d1 = &xl[row * X2STR + q * 32];
    u16* d2 = &xl[row * X2STR + 128 + q * 32];
#pragma unroll
    for (int i = 0; i < 8; ++i) {
      *reinterpret_cast<ushort4*>(d1 + i * 4) = cvt4(s1[i]);
      *reinterpret_cast<ushort4*>(d2 + i * 4) = cvt4(s2[i]);
    }
  }
  __syncthreads();

  const int w = tid >> 6;
  const int l = tid & 63;
  const int lr = l & 15;
  const int lk = (l >> 4) << 3;
  const int n0 = w * 32 + lr;
  const int rowh = (l >> 4) << 2;

  f32x4 acc[4][2] = {};
#pragma unroll 1
  for (int ks = 0; ks < 8; ++ks) {
    const int k0 = ks * 32;
    bf16x8 a[4], b[2];
#pragma unroll
    for (int rt = 0; rt < 4; ++rt)
      a[rt] = *reinterpret_cast<const bf16x8*>(&xl[(rt * 16 + lr) * X2STR + k0 + lk]);
#pragma unroll
    for (int ct = 0; ct < 2; ++ct)
      b[ct] = *reinterpret_cast<const bf16x8*>(&W1T[(size_t)(n0 + ct * 16) * 256 + k0 + lk]);
#pragma unroll
    for (int rt = 0; rt < 4; ++rt)
#pragma unroll
      for (int ct = 0; ct < 2; ++ct)
        acc[rt][ct] = MFMA16(a[rt], b[ct], acc[rt][ct]);
  }

  {
    const float b1v0 = b1[n0], b1v1 = b1[n0 + 16];
#pragma unroll
    for (int rt = 0; rt < 4; ++rt)
#pragma unroll
      for (int ct = 0; ct < 2; ++ct) {
        const float bb = ct ? b1v1 : b1v0;
#pragma unroll
        for (int j = 0; j < 4; ++j) {
          float v = acc[rt][ct][j] + bb;
          v = v / (1.f + __expf(-v));
          hl[(rt * 16 + rowh + j) * HSTR + n0 + ct * 16] = f2bf(v);
        }
      }
  }
  __syncthreads();

  f32x4 acc2[4][2] = {};
#pragma unroll
  for (int ks = 0; ks < 4; ++ks) {
    const int k0 = ks * 32;
    bf16x8 a[4], b[2];
#pragma unroll
    for (int rt = 0; rt < 4; ++rt)
      a[rt] = *reinterpret_cast<const bf16x8*>(&hl[(rt * 16 + lr) * HSTR + k0 + lk]);
#pragma unroll
    for (int ct = 0; ct < 2; ++ct)
      b[ct] = *reinterpret_cast<const bf16x8*>(&W2T[(size_t)(n0 + ct * 16) * 128 + k0 + lk]);
#pragma unroll
    for (int rt = 0; rt < 4; ++rt)
#pragma unroll
      for (int ct = 0; ct < 2; ++ct)
        acc2[rt][ct] = MFMA16(a[rt], b[ct], acc2[rt][ct]);
  }

  {
    const float b2v0 = b2[n0], b2v1 = b2[n0 + 16];
#pragma unroll
    for (int rt = 0; rt < 4; ++rt)
#pragma unroll
      for (int j = 0; j < 4; ++j) {
        const int row = rt * 16 + rowh + j;
        const int r = r0 + row;
        if (r < NP) {
          out[(size_t)r * 128 + n0]      = h_pair[(size_t)r * 128 + n0]      + acc2[rt][0][j] + b2v0;
          out[(size_t)r * 128 + n0 + 16] = h_pair[(size_t)r * 128 + n0 + 16] + acc2[rt][1][j] + b2v1;
        }
      }
  }
}

extern "C" void kernel_launch(void* const* d_in, const int* in_sizes, int n_in,
                              void* d_out, int out_size, void* d_ws, size_t ws_size,
                              hipStream_t stream) {
  const float* h_pair = (const float*)d_in[0];
  const int* ivu = (const int*)d_in[1];
  const int* iuw = (const int*)d_in[2];
  const int* ivw = (const int*)d_in[3];
  const float* geom = (const float*)d_in[4];
  const float* psi_w1 = (const float*)d_in[5];
  const float* psi_b1 = (const float*)d_in[6];
  const float* psi_w2 = (const float*)d_in[7];
  const float* psi_b2 = (const float*)d_in[8];
  const float* phi_w1 = (const float*)d_in[9];
  const float* phi_b1 = (const float*)d_in[10];
  const float* phi_w2 = (const float*)d_in[11];
  const float* phi_b2 = (const float*)d_in[12];

  float* out = (float*)d_out;
  u16* ws = (u16*)d_ws;
  char* wsb = (char*)d_ws;

  if (ws_size >= WS_S3) {
    int*  cnt    = (int*)(wsb + SB_CNT2);
    int*  cursor = (int*)(wsb + SB_CURSOR2);
    int*  bsum   = (int*)(wsb + SB_BSUM2);
    int4* trip   = (int4*)(wsb + SB_TRIP);
    u32*  YA     = (u32*)(wsb + SB_YA);
    u32*  YB     = (u32*)(wsb + SB_YB);
    u32*  YC     = (u32*)(wsb + SB_YC);

    hipMemsetAsync(cnt, 0, NP * sizeof(int), stream);
    k_pre3<<<5529, 256, 0, stream>>>(psi_w1, psi_w2, phi_w1, phi_w2, ivw, ws, cnt);
    k_scan1<<<98, 1024, 0, stream>>>(cnt, cursor, bsum);
    k_scan2<<<1, 128, 0, stream>>>(bsum);
    k_perm_pack<<<1954, 256, 0, stream>>>(ivu, iuw, ivw, geom, cursor, bsum, trip);
    k_proj<<<1563, 256, 0, stream>>>(h_pair, ws + FP_W1A, ws + FP_W1B, ws + FP_W1C,
                                     ws + FP_H, YA, YB, YC);
    k_gsilu2<<<(NBATCH + 3) / 4, 256, 0, stream>>>(
        YA, YB, YC, (const u32*)trip,
        reinterpret_cast<const float*>(ws + FP_W1D), psi_b1, ws + FP_AGG);
    k_pair2<<<1563, 256, 0, stream>>>(
        h_pair, ws + FP_H, ws + FP_AGG, cnt, ws + FP_W2,
        ws + FP_PW1, ws + FP_PW2, psi_b2, phi_b1, phi_b2, out);
  } else {
    hipMemsetAsync(d_out, 0, (size_t)out_size * sizeof(float), stream);
    k_prep<<<(WS_U16_TOTAL + 255) / 256, 256, 0, stream>>>(psi_w1, psi_w2, phi_w1, phi_w2, ws);
    k_triplet<<<(T_TRIP + 63) / 64, 256, 0, stream>>>(
        h_pair, ivu, iuw, ivw, geom,
        ws + PSI_W1T_OFF, ws + PSI_W2T_OFF, psi_b1, psi_b2, out);
    k_pair<<<(NP + 63) / 64, 256, 0, stream>>>(
        h_pair, ws + PHI_W1T_OFF, ws + PHI_W2T_OFF, phi_b1, phi_b2, out);
  }
}

// Round 13
// 249.624 us; speedup vs baseline: 1.0276x; 1.0276x over previous
//
#include <hip/hip_runtime.h>
#include <hip/hip_bf16.h>

#define T_TRIP 500000
#define NP     100000
#define NPAD   500032
#define NBATCH 31252   // NPAD/16

typedef float f32x4 __attribute__((ext_vector_type(4)));
typedef __bf16 bf16x8 __attribute__((ext_vector_type(8)));
typedef unsigned short u16;
typedef unsigned short u16x8 __attribute__((ext_vector_type(8)));
typedef unsigned int u32;

__device__ __forceinline__ u16 f2bf(float f) {
  union { float f; unsigned u; } v; v.f = f;
  unsigned r = v.u + 0x7fffu + ((v.u >> 16) & 1u);
  return (u16)(r >> 16);
}

__device__ __forceinline__ ushort4 cvt4(float4 v) {
  ushort4 o; o.x = f2bf(v.x); o.y = f2bf(v.y); o.z = f2bf(v.z); o.w = f2bf(v.w);
  return o;
}

__device__ __forceinline__ u16 cvt1_pk(float v) {
  unsigned r;
  asm("v_cvt_pk_bf16_f32 %0, %1, %1" : "=v"(r) : "v"(v));
  return (u16)r;
}

__device__ __forceinline__ float bflo(u32 d) {
  union { u32 u; float f; } v; v.u = d << 16; return v.f;
}
__device__ __forceinline__ float bfhi(u32 d) {
  union { u32 u; float f; } v; v.u = d & 0xffff0000u; return v.f;
}

#define MFMA16(a, b, c) __builtin_amdgcn_mfma_f32_16x16x32_bf16((a), (b), (c), 0, 0, 0)
#define LGKM0()   asm volatile("s_waitcnt lgkmcnt(0)" ::: "memory")

// =================== ws layout ===================
#define FP_W1A   0u
#define FP_W1B   16384u
#define FP_W1C   32768u
#define FP_W2    49152u     // PERMUTED K layout (pi)
#define FP_PW1   65536u
#define FP_PW2   98304u
#define FP_W1D   114688u    // f32 [4][128]
#define FP_AGG   12931072u  // Hagg bf16 [NP][128] (PERMUTED col layout)
#define SB_CNT2    51462144ull
#define SB_CURSOR2 51862144ull
#define SB_BSUM2   52262144ull
#define SB_TRIP    52262656ull          // 16B packed AoS per triplet
#define SB_YA      60263168ull          // u32 [NP][64] dword q <-> cols (c0(q), c0(q)+16)
#define SB_YB      85863168ull
#define SB_YC     111463168ull
#define WS_S3     137063168ull

#define HSTR   136
#define X2STR  264

// permuted-K map: u16 position i <-> column pi(i)
__device__ __host__ __forceinline__ int pi_col(int i) {
  int q = i >> 1;
  return ((q >> 4) << 5) + (q & 15) + ((i & 1) << 4);
}

// ---------------- pre: weights prep + zero Hagg + histogram ----------------
__global__ void k_pre3(const float* __restrict__ psi_w1, const float* __restrict__ psi_w2,
                       const float* __restrict__ phi_w1, const float* __restrict__ phi_w2,
                       const int* __restrict__ ivw,
                       u16* __restrict__ ws, int* __restrict__ cnt) {
  const int b = blockIdx.x;
  if (b < 450) {
    int i = b * 256 + threadIdx.x;
    if (i < 49152) {
      int s = i / 16384, r = i % 16384;
      int n = r / 128, k = r % 128;
      ws[FP_W1A + i] = f2bf(psi_w1[(s * 128 + k) * 128 + n]);
      return;
    }
    i -= 49152;
    if (i < 16384) {                       // W2T with K permuted by pi
      int n = i / 128, k = i % 128;
      ws[FP_W2 + i] = f2bf(psi_w2[pi_col(k) * 128 + n]);
      return;
    }
    i -= 16384;
    if (i < 32768) {
      int n = i / 256, k = i % 256;
      ws[FP_PW1 + i] = f2bf(phi_w1[k * 128 + n]);
      return;
    }
    i -= 32768;
    if (i < 16384) {
      int n = i / 128, k = i % 128;
      ws[FP_PW2 + i] = f2bf(phi_w2[k * 128 + n]);
      return;
    }
    i -= 16384;
    if (i < 512) {
      int k = i / 128, n = i % 128;
      reinterpret_cast<float*>(ws + FP_W1D)[i] = psi_w1[(384 + k) * 128 + n];
    }
  } else if (b < 3575) {
    const size_t i = (size_t)((b - 450) * 256 + threadIdx.x) * 16;
    ushort4 z = {0, 0, 0, 0};
    u16* d = ws + FP_AGG + i;
#pragma unroll
    for (int k = 0; k < 4; ++k) *reinterpret_cast<ushort4*>(d + k * 4) = z;
  } else {
    int i = (b - 3575) * 256 + threadIdx.x;
    if (i < T_TRIP) atomicAdd(&cnt[ivw[i]], 1);
  }
}

// ================= scan =================
__global__ __launch_bounds__(1024) void k_scan1(const int* __restrict__ cnt,
                                                int* __restrict__ cursor, int* __restrict__ bsum) {
  __shared__ int wsum[16];
  const int idx = blockIdx.x * 1024 + threadIdx.x;
  const int lane = threadIdx.x & 63, wid = threadIdx.x >> 6;
  int v = (idx < NP) ? cnt[idx] : 0;
  int x = v;
#pragma unroll
  for (int off = 1; off < 64; off <<= 1) {
    int n = __shfl_up(x, off);
    if (lane >= off) x += n;
  }
  if (lane == 63) wsum[wid] = x;
  __syncthreads();
  if (threadIdx.x < 16) {
    int s = wsum[threadIdx.x];
#pragma unroll
    for (int off = 1; off < 16; off <<= 1) {
      int n = __shfl_up(s, off);
      if (threadIdx.x >= off) s += n;
    }
    wsum[threadIdx.x] = s;
  }
  __syncthreads();
  const int base = wid ? wsum[wid - 1] : 0;
  if (idx < NP) cursor[idx] = base + x - v;
  if (threadIdx.x == 1023) bsum[blockIdx.x] = base + x;
}

__global__ void k_scan2(int* __restrict__ bsum) {
  __shared__ int s[128];
  const int t = threadIdx.x;
  int v = (t < 98) ? bsum[t] : 0;
  s[t] = v; __syncthreads();
#pragma unroll
  for (int off = 1; off < 128; off <<= 1) {
    int a = (t >= off) ? s[t - off] : 0;
    __syncthreads();
    s[t] += a;
    __syncthreads();
  }
  if (t < 98) bsum[t] = s[t] - v;
}

// ================= permute -> 16B packed AoS =================
__global__ void k_perm_pack(const int* __restrict__ ivu, const int* __restrict__ iuw,
                            const int* __restrict__ ivw, const float* __restrict__ geom,
                            int* __restrict__ cursor, const int* __restrict__ bsum,
                            int4* __restrict__ trip) {
  int i = blockIdx.x * 256 + threadIdx.x;
  if (i < T_TRIP) {
    int v = ivw[i];
    int pos = atomicAdd(&cursor[v], 1) + bsum[v >> 10];
    float4 g = reinterpret_cast<const float4*>(geom)[i];
    u32 pk0, pk1;
    asm("v_cvt_pk_bf16_f32 %0, %1, %2" : "=v"(pk0) : "v"(g.x), "v"(g.y));
    asm("v_cvt_pk_bf16_f32 %0, %1, %2" : "=v"(pk1) : "v"(g.z), "v"(g.w));
    int4 rec;
    rec.x = ivu[i] | ((v & 0x7fff) << 17);
    rec.y = iuw[i] | ((v >> 15) << 17);
    rec.z = (int)pk0;
    rec.w = (int)pk1;
    trip[pos] = rec;
  } else if (i < NPAD) {
    int4 z = {0, 0, 0, 0};
    trip[i] = z;
  }
}

// ================= proj: Y_{a,b,c} = bf16(h) @ W1{a,b,c}^T (no H materialization) =================
__global__ __launch_bounds__(256, 4) void k_proj(
    const float* __restrict__ h, const u16* __restrict__ W1A, const u16* __restrict__ W1B,
    const u16* __restrict__ W1C,
    u32* __restrict__ YA, u32* __restrict__ YB, u32* __restrict__ YC) {
  __shared__ __align__(16) u16 xs[64 * 132];
  const int tid = threadIdx.x;
  const int r0 = blockIdx.x * 64;
  {
    const int row = tid >> 2, q = tid & 3;
    int rc = r0 + row; rc = (rc < NP) ? rc : (NP - 1);
    const float4* src = reinterpret_cast<const float4*>(h + (size_t)rc * 128 + q * 32);
    u16* ldst = &xs[row * 132 + q * 32];
#pragma unroll
    for (int i = 0; i < 8; ++i)
      *reinterpret_cast<ushort4*>(ldst + i * 4) = cvt4(src[i]);
  }
  __syncthreads();
  const int w = tid >> 6, l = tid & 63;
  const int lr = l & 15, lk = (l >> 4) << 3;
  const int n0 = w * 32 + lr;
  const int rowh = (l >> 4) << 2;
  const int qd = w * 16 + lr;                  // Y dword index: c0(qd) == n0

  const u16* WT[3] = {W1A, W1B, W1C};
  u32* YT[3] = {YA, YB, YC};
#pragma unroll
  for (int s = 0; s < 3; ++s) {
    f32x4 acc[4][2] = {};
#pragma unroll
    for (int ks = 0; ks < 4; ++ks) {
      bf16x8 a[4], b[2];
#pragma unroll
      for (int rt = 0; rt < 4; ++rt)
        a[rt] = *reinterpret_cast<const bf16x8*>(&xs[(rt * 16 + lr) * 132 + ks * 32 + lk]);
#pragma unroll
      for (int ct = 0; ct < 2; ++ct)
        b[ct] = *reinterpret_cast<const bf16x8*>(&WT[s][(size_t)(n0 + ct * 16) * 128 + ks * 32 + lk]);
#pragma unroll
      for (int rt = 0; rt < 4; ++rt)
#pragma unroll
        for (int ct = 0; ct < 2; ++ct)
          acc[rt][ct] = MFMA16(a[rt], b[ct], acc[rt][ct]);
    }
#pragma unroll
    for (int rt = 0; rt < 4; ++rt)
#pragma unroll
      for (int j = 0; j < 4; ++j) {
        const int row = rt * 16 + rowh + j;
        if (r0 + row < NP) {
          u32 pk;
          asm("v_cvt_pk_bf16_f32 %0, %1, %2" : "=v"(pk) : "v"(acc[rt][0][j]), "v"(acc[rt][1][j]));
          YT[s][(size_t)(r0 + row) * 64 + qd] = pk;
        }
      }
  }
}

// ================= gsilu2: gather + silu + run-reduce; plain stores for interior runs =================
__global__ void k_gsilu2(
    const u32* __restrict__ YA, const u32* __restrict__ YB, const u32* __restrict__ YC,
    const u32* __restrict__ tripw, const float* __restrict__ w1dF,
    const float* __restrict__ b1, u16* __restrict__ Hagg) {
  const int w = threadIdx.x >> 6, l = threadIdx.x & 63;
  const int batch = blockIdx.x * 4 + w;
  if (batch >= NBATCH) return;
  const int t0 = batch * 16;
  const int c0 = ((l >> 4) << 5) + (l & 15);

  const u32 aos = tripw[(size_t)batch * 64 + l];

  float wd[4][2];
#pragma unroll
  for (int k = 0; k < 4; ++k) {
    wd[k][0] = w1dF[k * 128 + c0];
    wd[k][1] = w1dF[k * 128 + c0 + 16];
  }
  const float bb0 = b1[c0], bb1 = b1[c0 + 16];

  int vw[16];
  u32 g2[16], g3[16], ga[16], gb[16];
#pragma unroll
  for (int i = 0; i < 16; ++i) {
    const u32 d0 = (u32)__shfl((int)aos, i * 4);
    const u32 d1 = (u32)__shfl((int)aos, i * 4 + 1);
    g2[i] = (u32)__shfl((int)aos, i * 4 + 2);
    g3[i] = (u32)__shfl((int)aos, i * 4 + 3);
    vw[i] = (int)((d0 >> 17) | ((d1 >> 17) << 15));
    ga[i] = YA[(size_t)(d0 & 0x1FFFF) * 64 + l];
    gb[i] = YB[(size_t)(d1 & 0x1FFFF) * 64 + l];
  }

  int prevVw = -1, nextVw = -1;
  if (t0 > 0) {
    u32 pd0 = tripw[(size_t)(t0 - 1) * 4];
    u32 pd1 = tripw[(size_t)(t0 - 1) * 4 + 1];
    prevVw = (int)((pd0 >> 17) | ((pd1 >> 17) << 15));
  }
  if (t0 + 16 < T_TRIP) {
    u32 nd0 = tripw[(size_t)(t0 + 16) * 4];
    u32 nd1 = tripw[(size_t)(t0 + 16) * 4 + 1];
    nextVw = (int)((nd0 >> 17) | ((nd1 >> 17) << 15));
  }

  float lo = 0.f, hi = 0.f;
  u32 gcc = 0;
  int istart = 0;
#pragma unroll
  for (int i = 0; i < 16; ++i) {
    const bool runStart = (i == 0) || (vw[i] != vw[i - 1]);
    if (runStart) {
      istart = i;
      gcc = YC[(size_t)vw[i] * 64 + l];
    }
    if (t0 + i < T_TRIP) {
      const float gx = bflo(g2[i]), gy = bfhi(g2[i]), gz = bflo(g3[i]), gw4 = bfhi(g3[i]);
      float p0 = bflo(ga[i]) + bflo(gb[i]) + bflo(gcc) + bb0
               + gx * wd[0][0] + gy * wd[1][0] + gz * wd[2][0] + gw4 * wd[3][0];
      float p1 = bfhi(ga[i]) + bfhi(gb[i]) + bfhi(gcc) + bb1
               + gx * wd[0][1] + gy * wd[1][1] + gz * wd[2][1] + gw4 * wd[3][1];
      lo += p0 * __builtin_amdgcn_rcpf(1.f + __expf(-p0));
      hi += p1 * __builtin_amdgcn_rcpf(1.f + __expf(-p1));
    }
    bool doflush;
    if (i == 15) doflush = true;
    else doflush = (vw[i + 1] != vw[i]);
    if (doflush && (t0 + istart < T_TRIP)) {
      const bool contL = (istart == 0) && (vw[i] == prevVw);
      const bool contR = (i == 15) && (vw[i] == nextVw);
      u16* p = Hagg + (size_t)vw[i] * 128 + l * 2;   // permuted position, matches W2T pi
      u32 pk;
      asm("v_cvt_pk_bf16_f32 %0, %1, %2" : "=v"(pk) : "v"(lo), "v"(hi));
      if (contL || contR) {
        asm volatile("global_atomic_pk_add_bf16 %0, %1, off" :: "v"(p), "v"(pk) : "memory");
      } else {
        *reinterpret_cast<u32*>(p) = pk;
      }
      lo = 0.f; hi = 0.f;
    }
  }
}

// ================= pair2: agg = Hagg@W2 + cnt*b2; out = h + phi([bf16(h)|agg]) =================
__global__ __launch_bounds__(256, 3) void k_pair2(
    const float* __restrict__ h_pair, const u16* __restrict__ Hagg,
    const int* __restrict__ cnt, const u16* __restrict__ W2T,
    const u16* __restrict__ PW1T, const u16* __restrict__ PW2T,
    const float* __restrict__ psi_b2, const float* __restrict__ b1, const float* __restrict__ b2,
    float* __restrict__ out) {
  __shared__ __align__(16) u16 xl[64 * X2STR];
  __shared__ __align__(16) u16 hl[64 * HSTR];
  u32* xl32 = reinterpret_cast<u32*>(xl);

  const int tid = threadIdx.x;
  const int r0 = blockIdx.x * 64;

  {
    const int row = tid >> 2, q = tid & 3;
    int rc = r0 + row; rc = (rc < NP) ? rc : (NP - 1);
    const float4* sh = reinterpret_cast<const float4*>(h_pair + (size_t)rc * 128 + q * 32);
    const u16x8* sa = reinterpret_cast<const u16x8*>(Hagg + (size_t)rc * 128 + q * 32);
    u16* d1 = &xl[row * X2STR + q * 32];
    u16x8* d2 = reinterpret_cast<u16x8*>(&hl[row * HSTR + q * 32]);
#pragma unroll
    for (int i = 0; i < 8; ++i)
      *reinterpret_cast<ushort4*>(d1 + i * 4) = cvt4(sh[i]);
#pragma unroll
    for (int i = 0; i < 4; ++i) d2[i] = sa[i];
  }
  __syncthreads();

  const int w = tid >> 6, l = tid & 63;
  const int lr = l & 15, lk = (l >> 4) << 3;
  const int n0 = w * 32 + lr;
  const int rowh = (l >> 4) << 2;

  // ---- front GEMM: agg = Hagg_perm @ W2T_perm + cnt*psi_b2 -> xl cols 128..255 ----
  {
    f32x4 acc[4][2] = {};
#pragma unroll
    for (int ks = 0; ks < 4; ++ks) {
      bf16x8 a[4], b[2];
#pragma unroll
      for (int rt = 0; rt < 4; ++rt)
        a[rt] = *reinterpret_cast<const bf16x8*>(&hl[(rt * 16 + lr) * HSTR + ks * 32 + lk]);
#pragma unroll
      for (int ct = 0; ct < 2; ++ct)
        b[ct] = *reinterpret_cast<const bf16x8*>(&W2T[(size_t)(n0 + ct * 16) * 128 + ks * 32 + lk]);
#pragma unroll
      for (int rt = 0; rt < 4; ++rt)
#pragma unroll
        for (int ct = 0; ct < 2; ++ct)
          acc[rt][ct] = MFMA16(a[rt], b[ct], acc[rt][ct]);
    }
    const float pb2v[2] = {psi_b2[n0], psi_b2[n0 + 16]};
#pragma unroll
    for (int rt = 0; rt < 4; ++rt)
#pragma unroll
      for (int j = 0; j < 4; ++j) {
        const int row = rt * 16 + rowh + j;
        int rc = r0 + row; rc = (rc < NP) ? rc : (NP - 1);
        const float cf = (float)cnt[rc];
        float v0 = acc[rt][0][j] + cf * pb2v[0];
        float v1 = acc[rt][1][j] + cf * pb2v[1];
        float x0 = __shfl_xor(v0, 1), x1 = __shfl_xor(v1, 1);
        const bool even = (l & 1) == 0;
        float lo = even ? v0 : x1, hi = even ? x0 : v1;
        const int dcol = even ? (n0 >> 1) : ((n0 + 15) >> 1);
        u32 pk;
        asm("v_cvt_pk_bf16_f32 %0, %1, %2" : "=v"(pk) : "v"(lo), "v"(hi));
        xl32[row * (X2STR / 2) + 64 + dcol] = pk;
      }
  }
  LGKM0();
  __syncthreads();

  // ---- phi GEMM1 (K=256) ----
  f32x4 acc[4][2] = {};
#pragma unroll 1
  for (int ks = 0; ks < 8; ++ks) {
    const int k0 = ks * 32;
    bf16x8 a[4], b[2];
#pragma unroll
    for (int rt = 0; rt < 4; ++rt)
      a[rt] = *reinterpret_cast<const bf16x8*>(&xl[(rt * 16 + lr) * X2STR + k0 + lk]);
#pragma unroll
    for (int ct = 0; ct < 2; ++ct)
      b[ct] = *reinterpret_cast<const bf16x8*>(&PW1T[(size_t)(n0 + ct * 16) * 256 + k0 + lk]);
#pragma unroll
    for (int rt = 0; rt < 4; ++rt)
#pragma unroll
      for (int ct = 0; ct < 2; ++ct)
        acc[rt][ct] = MFMA16(a[rt], b[ct], acc[rt][ct]);
  }

  {
    const float b1v0 = b1[n0], b1v1 = b1[n0 + 16];
#pragma unroll
    for (int rt = 0; rt < 4; ++rt)
#pragma unroll
      for (int ct = 0; ct < 2; ++ct) {
        const float bb = ct ? b1v1 : b1v0;
#pragma unroll
        for (int j = 0; j < 4; ++j) {
          float v = acc[rt][ct][j] + bb;
          v = v * __builtin_amdgcn_rcpf(1.f + __expf(-v));
          hl[(rt * 16 + rowh + j) * HSTR + n0 + ct * 16] = cvt1_pk(v);
        }
      }
  }
  __syncthreads();

  // ---- phi GEMM2 ----
  f32x4 acc2[4][2] = {};
#pragma unroll
  for (int ks = 0; ks < 4; ++ks) {
    const int k0 = ks * 32;
    bf16x8 a[4], b[2];
#pragma unroll
    for (int rt = 0; rt < 4; ++rt)
      a[rt] = *reinterpret_cast<const bf16x8*>(&hl[(rt * 16 + lr) * HSTR + k0 + lk]);
#pragma unroll
    for (int ct = 0; ct < 2; ++ct)
      b[ct] = *reinterpret_cast<const bf16x8*>(&PW2T[(size_t)(n0 + ct * 16) * 128 + k0 + lk]);
#pragma unroll
    for (int rt = 0; rt < 4; ++rt)
#pragma unroll
      for (int ct = 0; ct < 2; ++ct)
        acc2[rt][ct] = MFMA16(a[rt], b[ct], acc2[rt][ct]);
  }

  {
    const float b2v0 = b2[n0], b2v1 = b2[n0 + 16];
#pragma unroll
    for (int rt = 0; rt < 4; ++rt)
#pragma unroll
      for (int j = 0; j < 4; ++j) {
        const int row = rt * 16 + rowh + j;
        const int r = r0 + row;
        if (r < NP) {
          out[(size_t)r * 128 + n0]      = h_pair[(size_t)r * 128 + n0]      + acc2[rt][0][j] + b2v0;
          out[(size_t)r * 128 + n0 + 16] = h_pair[(size_t)r * 128 + n0 + 16] + acc2[rt][1][j] + b2v1;
        }
      }
  }
}

// ===================== R0 fallback (tiny ws) =====================
#define PSI_W1T_OFF 0
#define PSI_W2T_OFF 53248
#define PHI_W1T_OFF 69632
#define PHI_W2T_OFF 102400
#define WS_U16_TOTAL 118784
#define XSTR 424

__global__ void k_prep(const float* __restrict__ psi_w1, const float* __restrict__ psi_w2,
                       const float* __restrict__ phi_w1, const float* __restrict__ phi_w2,
                       u16* __restrict__ ws) {
  int i = blockIdx.x * 256 + threadIdx.x;
  if (i < 128 * 416) {
    int n = i / 416, k = i % 416;
    ws[PSI_W1T_OFF + i] = f2bf(k < 388 ? psi_w1[k * 128 + n] : 0.f);
    return;
  }
  i -= 128 * 416;
  if (i < 128 * 128) {
    int n = i / 128, k = i % 128;
    ws[PSI_W2T_OFF + i] = f2bf(psi_w2[k * 128 + n]);
    return;
  }
  i -= 128 * 128;
  if (i < 128 * 256) {
    int n = i / 256, k = i % 256;
    ws[PHI_W1T_OFF + i] = f2bf(phi_w1[k * 128 + n]);
    return;
  }
  i -= 128 * 256;
  if (i < 128 * 128) {
    int n = i / 128, k = i % 128;
    ws[PHI_W2T_OFF + i] = f2bf(phi_w2[k * 128 + n]);
  }
}

__global__ __launch_bounds__(256, 2) void k_triplet(
    const float* __restrict__ h_pair,
    const int* __restrict__ ivu, const int* __restrict__ iuw, const int* __restrict__ ivw,
    const float* __restrict__ geom,
    const u16* __restrict__ W1T, const u16* __restrict__ W2T,
    const float* __restrict__ b1, const float* __restrict__ b2,
    float* __restrict__ agg) {
  __shared__ __align__(16) u16 xl[64 * XSTR];
  __shared__ __align__(16) u16 hl[64 * HSTR];
  __shared__ int svw[64];

  const int tid = threadIdx.x;
  const int t0 = blockIdx.x * 64;

  {
    const int row = tid >> 2, q = tid & 3;
    const int t = t0 + row;
    const int tc = (t < T_TRIP) ? t : (T_TRIP - 1);
    if (q == 0) svw[row] = (t < T_TRIP) ? ivw[tc] : -1;
    int idx[3];
    idx[0] = ivu[tc]; idx[1] = iuw[tc]; idx[2] = ivw[tc];
#pragma unroll
    for (int s = 0; s < 3; ++s) {
      const float4* src = reinterpret_cast<const float4*>(h_pair + (size_t)idx[s] * 128 + q * 32);
      u16* dst = &xl[row * XSTR + s * 128 + q * 32];
#pragma unroll
      for (int i = 0; i < 8; ++i)
        *reinterpret_cast<ushort4*>(dst + i * 4) = cvt4(src[i]);
    }
  }
  if (tid < 64) {
    const int t = t0 + tid;
    const int tc = (t < T_TRIP) ? t : (T_TRIP - 1);
    const float4 g = reinterpret_cast<const float4*>(geom)[tc];
    u16* dst = &xl[tid * XSTR + 384];
    *reinterpret_cast<ushort4*>(dst) = cvt4(g);
    ushort4 z = {0, 0, 0, 0};
#pragma unroll
    for (int i = 1; i < 8; ++i) *reinterpret_cast<ushort4*>(dst + i * 4) = z;
  }
  __syncthreads();

  const int w = tid >> 6;
  const int l = tid & 63;
  const int lr = l & 15;
  const int lk = (l >> 4) << 3;
  const int n0 = w * 32 + lr;
  const int rowh = (l >> 4) << 2;

  f32x4 acc[4][2] = {};
#pragma unroll 1
  for (int ks = 0; ks < 13; ++ks) {
    const int k0 = ks * 32;
    bf16x8 a[4], b[2];
#pragma unroll
    for (int rt = 0; rt < 4; ++rt)
      a[rt] = *reinterpret_cast<const bf16x8*>(&xl[(rt * 16 + lr) * XSTR + k0 + lk]);
#pragma unroll
    for (int ct = 0; ct < 2; ++ct)
      b[ct] = *reinterpret_cast<const bf16x8*>(&W1T[(size_t)(n0 + ct * 16) * 416 + k0 + lk]);
#pragma unroll
    for (int rt = 0; rt < 4; ++rt)
#pragma unroll
      for (int ct = 0; ct < 2; ++ct)
        acc[rt][ct] = MFMA16(a[rt], b[ct], acc[rt][ct]);
  }

  {
    const float b1v0 = b1[n0], b1v1 = b1[n0 + 16];
#pragma unroll
    for (int rt = 0; rt < 4; ++rt)
#pragma unroll
      for (int ct = 0; ct < 2; ++ct) {
        const float bb = ct ? b1v1 : b1v0;
#pragma unroll
        for (int j = 0; j < 4; ++j) {
          float v = acc[rt][ct][j] + bb;
          v = v / (1.f + __expf(-v));
          hl[(rt * 16 + rowh + j) * HSTR + n0 + ct * 16] = f2bf(v);
        }
      }
  }
  __syncthreads();

  f32x4 acc2[4][2] = {};
#pragma unroll
  for (int ks = 0; ks < 4; ++ks) {
    const int k0 = ks * 32;
    bf16x8 a[4], b[2];
#pragma unroll
    for (int rt = 0; rt < 4; ++rt)
      a[rt] = *reinterpret_cast<const bf16x8*>(&hl[(rt * 16 + lr) * HSTR + k0 + lk]);
#pragma unroll
    for (int ct = 0; ct < 2; ++ct)
      b[ct] = *reinterpret_cast<const bf16x8*>(&W2T[(size_t)(n0 + ct * 16) * 128 + k0 + lk]);
#pragma unroll
    for (int rt = 0; rt < 4; ++rt)
#pragma unroll
      for (int ct = 0; ct < 2; ++ct)
        acc2[rt][ct] = MFMA16(a[rt], b[ct], acc2[rt][ct]);
  }

  {
    const float b2v0 = b2[n0], b2v1 = b2[n0 + 16];
#pragma unroll
    for (int rt = 0; rt < 4; ++rt)
#pragma unroll
      for (int j = 0; j < 4; ++j) {
        const int row = rt * 16 + rowh + j;
        const int dst = svw[row];
        if (dst >= 0) {
          unsafeAtomicAdd(&agg[(size_t)dst * 128 + n0], acc2[rt][0][j] + b2v0);
          unsafeAtomicAdd(&agg[(size_t)dst * 128 + n0 + 16], acc2[rt][1][j] + b2v1);
        }
      }
  }
}

__global__ __launch_bounds__(256, 2) void k_pair(
    const float* __restrict__ h_pair,
    const u16* __restrict__ W1T, const u16* __restrict__ W2T,
    const float* __restrict__ b1, const float* __restrict__ b2,
    float* __restrict__ out) {
  __shared__ __align__(16) u16 xl[64 * X2STR];
  __shared__ __align__(16) u16 hl[64 * HSTR];

  const int tid = threadIdx.x;
  const int r0 = blockIdx.x * 64;

  {
    const int row = tid >> 2, q = tid & 3;
    const int r = r0 + row;
    const int rc = (r < NP) ? r : (NP - 1);
    const float4* s1 = reinterpret_cast<const float4*>(h_pair + (size_t)rc * 128 + q * 32);
    const float4* s2 = reinterpret_cast<const float4*>(out + (size_t)rc * 128 + q * 32);
    u16* d1 = &xl[row * X2STR + q * 32];
    u16* d2 = &xl[row * X2STR + 128 + q * 32];
#pragma unroll
    for (int i = 0; i < 8; ++i) {
      *reinterpret_cast<ushort4*>(d1 + i * 4) = cvt4(s1[i]);
      *reinterpret_cast<ushort4*>(d2 + i * 4) = cvt4(s2[i]);
    }
  }
  __syncthreads();

  const int w = tid >> 6;
  const int l = tid & 63;
  const int lr = l & 15;
  const int lk = (l >> 4) << 3;
  const int n0 = w * 32 + lr;
  const int rowh = (l >> 4) << 2;

  f32x4 acc[4][2] = {};
#pragma unroll 1
  for (int ks = 0; ks < 8; ++ks) {
    const int k0 = ks * 32;
    bf16x8 a[4], b[2];
#pragma unroll
    for (int rt = 0; rt < 4; ++rt)
      a[rt] = *reinterpret_cast<const bf16x8*>(&xl[(rt * 16 + lr) * X2STR + k0 + lk]);
#pragma unroll
    for (int ct = 0; ct < 2; ++ct)
      b[ct] = *reinterpret_cast<const bf16x8*>(&W1T[(size_t)(n0 + ct * 16) * 256 + k0 + lk]);
#pragma unroll
    for (int rt = 0; rt < 4; ++rt)
#pragma unroll
      for (int ct = 0; ct < 2; ++ct)
        acc[rt][ct] = MFMA16(a[rt], b[ct], acc[rt][ct]);
  }

  {
    const float b1v0 = b1[n0], b1v1 = b1[n0 + 16];
#pragma unroll
    for (int rt = 0; rt < 4; ++rt)
#pragma unroll
      for (int ct = 0; ct < 2; ++ct) {
        const float bb = ct ? b1v1 : b1v0;
#pragma unroll
        for (int j = 0; j < 4; ++j) {
          float v = acc[rt][ct][j] + bb;
          v = v / (1.f + __expf(-v));
          hl[(rt * 16 + rowh + j) * HSTR + n0 + ct * 16] = f2bf(v);
        }
      }
  }
  __syncthreads();

  f32x4 acc2[4][2] = {};
#pragma unroll
  for (int ks = 0; ks < 4; ++ks) {
    const int k0 = ks * 32;
    bf16x8 a[4], b[2];
#pragma unroll
    for (int rt = 0; rt < 4; ++rt)
      a[rt] = *reinterpret_cast<const bf16x8*>(&hl[(rt * 16 + lr) * HSTR + k0 + lk]);
#pragma unroll
    for (int ct = 0; ct < 2; ++ct)
      b[ct] = *reinterpret_cast<const bf16x8*>(&W2T[(size_t)(n0 + ct * 16) * 128 + k0 + lk]);
#pragma unroll
    for (int rt = 0; rt < 4; ++rt)
#pragma unroll
      for (int ct = 0; ct < 2; ++ct)
        acc2[rt][ct] = MFMA16(a[rt], b[ct], acc2[rt][ct]);
  }

  {
    const float b2v0 = b2[n0], b2v1 = b2[n0 + 16];
#pragma unroll
    for (int rt = 0; rt < 4; ++rt)
#pragma unroll
      for (int j = 0; j < 4; ++j) {
        const int row = rt * 16 + rowh + j;
        const int r = r0 + row;
        if (r < NP) {
          out[(size_t)r * 128 + n0]      = h_pair[(size_t)r * 128 + n0]      + acc2[rt][0][j] + b2v0;
          out[(size_t)r * 128 + n0 + 16] = h_pair[(size_t)r * 128 + n0 + 16] + acc2[rt][1][j] + b2v1;
        }
      }
  }
}

extern "C" void kernel_launch(void* const* d_in, const int* in_sizes, int n_in,
                              void* d_out, int out_size, void* d_ws, size_t ws_size,
                              hipStream_t stream) {
  const float* h_pair = (const float*)d_in[0];
  const int* ivu = (const int*)d_in[1];
  const int* iuw = (const int*)d_in[2];
  const int* ivw = (const int*)d_in[3];
  const float* geom = (const float*)d_in[4];
  const float* psi_w1 = (const float*)d_in[5];
  const float* psi_b1 = (const float*)d_in[6];
  const float* psi_w2 = (const float*)d_in[7];
  const float* psi_b2 = (const float*)d_in[8];
  const float* phi_w1 = (const float*)d_in[9];
  const float* phi_b1 = (const float*)d_in[10];
  const float* phi_w2 = (const float*)d_in[11];
  const float* phi_b2 = (const float*)d_in[12];

  float* out = (float*)d_out;
  u16* ws = (u16*)d_ws;
  char* wsb = (char*)d_ws;

  if (ws_size >= WS_S3) {
    int*  cnt    = (int*)(wsb + SB_CNT2);
    int*  cursor = (int*)(wsb + SB_CURSOR2);
    int*  bsum   = (int*)(wsb + SB_BSUM2);
    int4* trip   = (int4*)(wsb + SB_TRIP);
    u32*  YA     = (u32*)(wsb + SB_YA);
    u32*  YB     = (u32*)(wsb + SB_YB);
    u32*  YC     = (u32*)(wsb + SB_YC);

    hipMemsetAsync(cnt, 0, NP * sizeof(int), stream);
    k_pre3<<<5529, 256, 0, stream>>>(psi_w1, psi_w2, phi_w1, phi_w2, ivw, ws, cnt);
    k_scan1<<<98, 1024, 0, stream>>>(cnt, cursor, bsum);
    k_scan2<<<1, 128, 0, stream>>>(bsum);
    k_perm_pack<<<1954, 256, 0, stream>>>(ivu, iuw, ivw, geom, cursor, bsum, trip);
    k_proj<<<1563, 256, 0, stream>>>(h_pair, ws + FP_W1A, ws + FP_W1B, ws + FP_W1C,
                                     YA, YB, YC);
    k_gsilu2<<<(NBATCH + 3) / 4, 256, 0, stream>>>(
        YA, YB, YC, (const u32*)trip,
        reinterpret_cast<const float*>(ws + FP_W1D), psi_b1, ws + FP_AGG);
    k_pair2<<<1563, 256, 0, stream>>>(
        h_pair, ws + FP_AGG, cnt, ws + FP_W2,
        ws + FP_PW1, ws + FP_PW2, psi_b2, phi_b1, phi_b2, out);
  } else {
    hipMemsetAsync(d_out, 0, (size_t)out_size * sizeof(float), stream);
    k_prep<<<(WS_U16_TOTAL + 255) / 256, 256, 0, stream>>>(psi_w1, psi_w2, phi_w1, phi_w2, ws);
    k_triplet<<<(T_TRIP + 63) / 64, 256, 0, stream>>>(
        h_pair, ivu, iuw, ivw, geom,
        ws + PSI_W1T_OFF, ws + PSI_W2T_OFF, psi_b1, psi_b2, out);
    k_pair<<<(NP + 63) / 64, 256, 0, stream>>>(
        h_pair, ws + PHI_W1T_OFF, ws + PHI_W2T_OFF, phi_b1, phi_b2, out);
  }
}

// Round 15
// 249.025 us; speedup vs baseline: 1.0301x; 1.0024x over previous
//
#include <hip/hip_runtime.h>
#include <hip/hip_bf16.h>

#define T_TRIP 500000
#define NP     100000
#define NPAD   500032
#define NBATCH 31252   // NPAD/16

typedef float f32x4 __attribute__((ext_vector_type(4)));
typedef __bf16 bf16x8 __attribute__((ext_vector_type(8)));
typedef unsigned short u16;
typedef unsigned short u16x8 __attribute__((ext_vector_type(8)));
typedef unsigned int u32;

__device__ __forceinline__ u16 f2bf(float f) {
  union { float f; unsigned u; } v; v.f = f;
  unsigned r = v.u + 0x7fffu + ((v.u >> 16) & 1u);
  return (u16)(r >> 16);
}

__device__ __forceinline__ ushort4 cvt4(float4 v) {
  ushort4 o; o.x = f2bf(v.x); o.y = f2bf(v.y); o.z = f2bf(v.z); o.w = f2bf(v.w);
  return o;
}

__device__ __forceinline__ u16 cvt1_pk(float v) {
  unsigned r;
  asm("v_cvt_pk_bf16_f32 %0, %1, %1" : "=v"(r) : "v"(v));
  return (u16)r;
}

__device__ __forceinline__ float bflo(u32 d) {
  union { u32 u; float f; } v; v.u = d << 16; return v.f;
}
__device__ __forceinline__ float bfhi(u32 d) {
  union { u32 u; float f; } v; v.u = d & 0xffff0000u; return v.f;
}

#define MFMA16(a, b, c) __builtin_amdgcn_mfma_f32_16x16x32_bf16((a), (b), (c), 0, 0, 0)
#define LGKM0()   asm volatile("s_waitcnt lgkmcnt(0)" ::: "memory")

// =================== ws layout ===================
#define FP_W1A   0u
#define FP_W1B   16384u
#define FP_W1C   32768u
#define FP_W2    49152u     // PERMUTED K layout (pi)
#define FP_PW1   65536u
#define FP_PW2   98304u
#define FP_W1D   114688u    // f32 [4][128]
#define FP_AGG   12931072u  // Hagg bf16 [NP][128] (PERMUTED col layout)
#define SB_CNT2    51462144ull
#define SB_CURSOR2 51862144ull
#define SB_BSUM2   52262144ull
#define SB_TRIP    52262656ull          // 16B packed AoS per triplet
#define SB_YA      60263168ull          // u32 [NP][64] dword q <-> cols (c0(q), c0(q)+16)
#define SB_YB      85863168ull
#define SB_YC     111463168ull
#define WS_S3     137063168ull

#define HSTR   136
#define X2STR  264

// permuted-K map: u16 position i <-> column pi(i)
__device__ __host__ __forceinline__ int pi_col(int i) {
  int q = i >> 1;
  return ((q >> 4) << 5) + (q & 15) + ((i & 1) << 4);
}

// ---------------- pre: weights prep + zero Hagg + histogram ----------------
__global__ void k_pre3(const float* __restrict__ psi_w1, const float* __restrict__ psi_w2,
                       const float* __restrict__ phi_w1, const float* __restrict__ phi_w2,
                       const int* __restrict__ ivw,
                       u16* __restrict__ ws, int* __restrict__ cnt) {
  const int b = blockIdx.x;
  if (b < 450) {
    int i = b * 256 + threadIdx.x;
    if (i < 49152) {
      int s = i / 16384, r = i % 16384;
      int n = r / 128, k = r % 128;
      ws[FP_W1A + i] = f2bf(psi_w1[(s * 128 + k) * 128 + n]);
      return;
    }
    i -= 49152;
    if (i < 16384) {                       // W2T with K permuted by pi
      int n = i / 128, k = i % 128;
      ws[FP_W2 + i] = f2bf(psi_w2[pi_col(k) * 128 + n]);
      return;
    }
    i -= 16384;
    if (i < 32768) {
      int n = i / 256, k = i % 256;
      ws[FP_PW1 + i] = f2bf(phi_w1[k * 128 + n]);
      return;
    }
    i -= 32768;
    if (i < 16384) {
      int n = i / 128, k = i % 128;
      ws[FP_PW2 + i] = f2bf(phi_w2[k * 128 + n]);
      return;
    }
    i -= 16384;
    if (i < 512) {
      int k = i / 128, n = i % 128;
      reinterpret_cast<float*>(ws + FP_W1D)[i] = psi_w1[(384 + k) * 128 + n];
    }
  } else if (b < 3575) {
    const size_t i = (size_t)((b - 450) * 256 + threadIdx.x) * 16;
    ushort4 z = {0, 0, 0, 0};
    u16* d = ws + FP_AGG + i;
#pragma unroll
    for (int k = 0; k < 4; ++k) *reinterpret_cast<ushort4*>(d + k * 4) = z;
  } else {
    int i = (b - 3575) * 256 + threadIdx.x;
    if (i < T_TRIP) atomicAdd(&cnt[ivw[i]], 1);
  }
}

// ================= scan =================
__global__ __launch_bounds__(1024) void k_scan1(const int* __restrict__ cnt,
                                                int* __restrict__ cursor, int* __restrict__ bsum) {
  __shared__ int wsum[16];
  const int idx = blockIdx.x * 1024 + threadIdx.x;
  const int lane = threadIdx.x & 63, wid = threadIdx.x >> 6;
  int v = (idx < NP) ? cnt[idx] : 0;
  int x = v;
#pragma unroll
  for (int off = 1; off < 64; off <<= 1) {
    int n = __shfl_up(x, off);
    if (lane >= off) x += n;
  }
  if (lane == 63) wsum[wid] = x;
  __syncthreads();
  if (threadIdx.x < 16) {
    int s = wsum[threadIdx.x];
#pragma unroll
    for (int off = 1; off < 16; off <<= 1) {
      int n = __shfl_up(s, off);
      if (threadIdx.x >= off) s += n;
    }
    wsum[threadIdx.x] = s;
  }
  __syncthreads();
  const int base = wid ? wsum[wid - 1] : 0;
  if (idx < NP) cursor[idx] = base + x - v;
  if (threadIdx.x == 1023) bsum[blockIdx.x] = base + x;
}

__global__ void k_scan2(int* __restrict__ bsum) {
  __shared__ int s[128];
  const int t = threadIdx.x;
  int v = (t < 98) ? bsum[t] : 0;
  s[t] = v; __syncthreads();
#pragma unroll
  for (int off = 1; off < 128; off <<= 1) {
    int a = (t >= off) ? s[t - off] : 0;
    __syncthreads();
    s[t] += a;
    __syncthreads();
  }
  if (t < 98) bsum[t] = s[t] - v;
}

// ================= permute -> 16B packed AoS =================
__global__ void k_perm_pack(const int* __restrict__ ivu, const int* __restrict__ iuw,
                            const int* __restrict__ ivw, const float* __restrict__ geom,
                            int* __restrict__ cursor, const int* __restrict__ bsum,
                            int4* __restrict__ trip) {
  int i = blockIdx.x * 256 + threadIdx.x;
  if (i < T_TRIP) {
    int v = ivw[i];
    int pos = atomicAdd(&cursor[v], 1) + bsum[v >> 10];
    float4 g = reinterpret_cast<const float4*>(geom)[i];
    u32 pk0, pk1;
    asm("v_cvt_pk_bf16_f32 %0, %1, %2" : "=v"(pk0) : "v"(g.x), "v"(g.y));
    asm("v_cvt_pk_bf16_f32 %0, %1, %2" : "=v"(pk1) : "v"(g.z), "v"(g.w));
    int4 rec;
    rec.x = ivu[i] | ((v & 0x7fff) << 17);
    rec.y = iuw[i] | ((v >> 15) << 17);
    rec.z = (int)pk0;
    rec.w = (int)pk1;
    trip[pos] = rec;
  } else if (i < NPAD) {
    int4 z = {0, 0, 0, 0};
    trip[i] = z;
  }
}

// ================= proj: Y_{a,b,c} = bf16(h) @ W1{a,b,c}^T (no H materialization) =================
__global__ __launch_bounds__(256, 4) void k_proj(
    const float* __restrict__ h, const u16* __restrict__ W1A, const u16* __restrict__ W1B,
    const u16* __restrict__ W1C,
    u32* __restrict__ YA, u32* __restrict__ YB, u32* __restrict__ YC) {
  __shared__ __align__(16) u16 xs[64 * 132];
  const int tid = threadIdx.x;
  const int r0 = blockIdx.x * 64;
  {
    const int row = tid >> 2, q = tid & 3;
    int rc = r0 + row; rc = (rc < NP) ? rc : (NP - 1);
    const float4* src = reinterpret_cast<const float4*>(h + (size_t)rc * 128 + q * 32);
    u16* ldst = &xs[row * 132 + q * 32];
#pragma unroll
    for (int i = 0; i < 8; ++i)
      *reinterpret_cast<ushort4*>(ldst + i * 4) = cvt4(src[i]);
  }
  __syncthreads();
  const int w = tid >> 6, l = tid & 63;
  const int lr = l & 15, lk = (l >> 4) << 3;
  const int n0 = w * 32 + lr;
  const int rowh = (l >> 4) << 2;
  const int qd = w * 16 + lr;                  // Y dword index: c0(qd) == n0

  const u16* WT[3] = {W1A, W1B, W1C};
  u32* YT[3] = {YA, YB, YC};
#pragma unroll
  for (int s = 0; s < 3; ++s) {
    f32x4 acc[4][2] = {};
#pragma unroll
    for (int ks = 0; ks < 4; ++ks) {
      bf16x8 a[4], b[2];
#pragma unroll
      for (int rt = 0; rt < 4; ++rt)
        a[rt] = *reinterpret_cast<const bf16x8*>(&xs[(rt * 16 + lr) * 132 + ks * 32 + lk]);
#pragma unroll
      for (int ct = 0; ct < 2; ++ct)
        b[ct] = *reinterpret_cast<const bf16x8*>(&WT[s][(size_t)(n0 + ct * 16) * 128 + ks * 32 + lk]);
#pragma unroll
      for (int rt = 0; rt < 4; ++rt)
#pragma unroll
        for (int ct = 0; ct < 2; ++ct)
          acc[rt][ct] = MFMA16(a[rt], b[ct], acc[rt][ct]);
    }
#pragma unroll
    for (int rt = 0; rt < 4; ++rt)
#pragma unroll
      for (int j = 0; j < 4; ++j) {
        const int row = rt * 16 + rowh + j;
        if (r0 + row < NP) {
          u32 pk;
          asm("v_cvt_pk_bf16_f32 %0, %1, %2" : "=v"(pk) : "v"(acc[rt][0][j]), "v"(acc[rt][1][j]));
          YT[s][(size_t)(r0 + row) * 64 + qd] = pk;
        }
      }
  }
}

// ================= gsilu2: gather + silu + run-reduce; plain stores for interior runs =================
__global__ void k_gsilu2(
    const u32* __restrict__ YA, const u32* __restrict__ YB, const u32* __restrict__ YC,
    const u32* __restrict__ tripw, const float* __restrict__ w1dF,
    const float* __restrict__ b1, u16* __restrict__ Hagg) {
  const int w = threadIdx.x >> 6, l = threadIdx.x & 63;
  const int batch = blockIdx.x * 4 + w;
  if (batch >= NBATCH) return;
  const int t0 = batch * 16;
  const int c0 = ((l >> 4) << 5) + (l & 15);

  const u32 aos = tripw[(size_t)batch * 64 + l];

  float wd[4][2];
#pragma unroll
  for (int k = 0; k < 4; ++k) {
    wd[k][0] = w1dF[k * 128 + c0];
    wd[k][1] = w1dF[k * 128 + c0 + 16];
  }
  const float bb0 = b1[c0], bb1 = b1[c0 + 16];

  int vw[16];
  u32 g2[16], g3[16], ga[16], gb[16];
#pragma unroll
  for (int i = 0; i < 16; ++i) {
    const u32 d0 = (u32)__shfl((int)aos, i * 4);
    const u32 d1 = (u32)__shfl((int)aos, i * 4 + 1);
    g2[i] = (u32)__shfl((int)aos, i * 4 + 2);
    g3[i] = (u32)__shfl((int)aos, i * 4 + 3);
    vw[i] = (int)((d0 >> 17) | ((d1 >> 17) << 15));
    ga[i] = YA[(size_t)(d0 & 0x1FFFF) * 64 + l];
    gb[i] = YB[(size_t)(d1 & 0x1FFFF) * 64 + l];
  }

  int prevVw = -1, nextVw = -1;
  if (t0 > 0) {
    u32 pd0 = tripw[(size_t)(t0 - 1) * 4];
    u32 pd1 = tripw[(size_t)(t0 - 1) * 4 + 1];
    prevVw = (int)((pd0 >> 17) | ((pd1 >> 17) << 15));
  }
  if (t0 + 16 < T_TRIP) {
    u32 nd0 = tripw[(size_t)(t0 + 16) * 4];
    u32 nd1 = tripw[(size_t)(t0 + 16) * 4 + 1];
    nextVw = (int)((nd0 >> 17) | ((nd1 >> 17) << 15));
  }

  float lo = 0.f, hi = 0.f;
  u32 gcc = 0;
  int istart = 0;
#pragma unroll
  for (int i = 0; i < 16; ++i) {
    const bool runStart = (i == 0) || (vw[i] != vw[i - 1]);
    if (runStart) {
      istart = i;
      gcc = YC[(size_t)vw[i] * 64 + l];
    }
    if (t0 + i < T_TRIP) {
      const float gx = bflo(g2[i]), gy = bfhi(g2[i]), gz = bflo(g3[i]), gw4 = bfhi(g3[i]);
      float p0 = bflo(ga[i]) + bflo(gb[i]) + bflo(gcc) + bb0
               + gx * wd[0][0] + gy * wd[1][0] + gz * wd[2][0] + gw4 * wd[3][0];
      float p1 = bfhi(ga[i]) + bfhi(gb[i]) + bfhi(gcc) + bb1
               + gx * wd[0][1] + gy * wd[1][1] + gz * wd[2][1] + gw4 * wd[3][1];
      lo += p0 * __builtin_amdgcn_rcpf(1.f + __expf(-p0));
      hi += p1 * __builtin_amdgcn_rcpf(1.f + __expf(-p1));
    }
    bool doflush;
    if (i == 15) doflush = true;
    else doflush = (vw[i + 1] != vw[i]);
    if (doflush && (t0 + istart < T_TRIP)) {
      const bool contL = (istart == 0) && (vw[i] == prevVw);
      const bool contR = (i == 15) && (vw[i] == nextVw);
      u16* p = Hagg + (size_t)vw[i] * 128 + l * 2;   // permuted position, matches W2T pi
      u32 pk;
      asm("v_cvt_pk_bf16_f32 %0, %1, %2" : "=v"(pk) : "v"(lo), "v"(hi));
      if (contL || contR) {
        asm volatile("global_atomic_pk_add_bf16 %0, %1, off" :: "v"(p), "v"(pk) : "memory");
      } else {
        *reinterpret_cast<u32*>(p) = pk;
      }
      lo = 0.f; hi = 0.f;
    }
  }
}

// ================= pair2: agg = Hagg@W2 + cnt*b2; out = h + phi([bf16(h)|agg]) =================
__global__ __launch_bounds__(256, 3) void k_pair2(
    const float* __restrict__ h_pair, const u16* __restrict__ Hagg,
    const int* __restrict__ cnt, const u16* __restrict__ W2T,
    const u16* __restrict__ PW1T, const u16* __restrict__ PW2T,
    const float* __restrict__ psi_b2, const float* __restrict__ b1, const float* __restrict__ b2,
    float* __restrict__ out) {
  __shared__ __align__(16) u16 xl[64 * X2STR];
  __shared__ __align__(16) u16 hl[64 * HSTR];
  u32* xl32 = reinterpret_cast<u32*>(xl);

  const int tid = threadIdx.x;
  const int r0 = blockIdx.x * 64;

  {
    const int row = tid >> 2, q = tid & 3;
    int rc = r0 + row; rc = (rc < NP) ? rc : (NP - 1);
    const float4* sh = reinterpret_cast<const float4*>(h_pair + (size_t)rc * 128 + q * 32);
    const u16x8* sa = reinterpret_cast<const u16x8*>(Hagg + (size_t)rc * 128 + q * 32);
    u16* d1 = &xl[row * X2STR + q * 32];
    u16x8* d2 = reinterpret_cast<u16x8*>(&hl[row * HSTR + q * 32]);
#pragma unroll
    for (int i = 0; i < 8; ++i)
      *reinterpret_cast<ushort4*>(d1 + i * 4) = cvt4(sh[i]);
#pragma unroll
    for (int i = 0; i < 4; ++i) d2[i] = sa[i];
  }
  __syncthreads();

  const int w = tid >> 6, l = tid & 63;
  const int lr = l & 15, lk = (l >> 4) << 3;
  const int n0 = w * 32 + lr;
  const int rowh = (l >> 4) << 2;

  // ---- front GEMM: agg = Hagg_perm @ W2T_perm + cnt*psi_b2 -> xl cols 128..255 ----
  {
    f32x4 acc[4][2] = {};
#pragma unroll
    for (int ks = 0; ks < 4; ++ks) {
      bf16x8 a[4], b[2];
#pragma unroll
      for (int rt = 0; rt < 4; ++rt)
        a[rt] = *reinterpret_cast<const bf16x8*>(&hl[(rt * 16 + lr) * HSTR + ks * 32 + lk]);
#pragma unroll
      for (int ct = 0; ct < 2; ++ct)
        b[ct] = *reinterpret_cast<const bf16x8*>(&W2T[(size_t)(n0 + ct * 16) * 128 + ks * 32 + lk]);
#pragma unroll
      for (int rt = 0; rt < 4; ++rt)
#pragma unroll
        for (int ct = 0; ct < 2; ++ct)
          acc[rt][ct] = MFMA16(a[rt], b[ct], acc[rt][ct]);
    }
    const float pb2v[2] = {psi_b2[n0], psi_b2[n0 + 16]};
#pragma unroll
    for (int rt = 0; rt < 4; ++rt)
#pragma unroll
      for (int j = 0; j < 4; ++j) {
        const int row = rt * 16 + rowh + j;
        int rc = r0 + row; rc = (rc < NP) ? rc : (NP - 1);
        const float cf = (float)cnt[rc];
        float v0 = acc[rt][0][j] + cf * pb2v[0];
        float v1 = acc[rt][1][j] + cf * pb2v[1];
        float x0 = __shfl_xor(v0, 1), x1 = __shfl_xor(v1, 1);
        const bool even = (l & 1) == 0;
        float lo = even ? v0 : x1, hi = even ? x0 : v1;
        const int dcol = even ? (n0 >> 1) : ((n0 + 15) >> 1);
        u32 pk;
        asm("v_cvt_pk_bf16_f32 %0, %1, %2" : "=v"(pk) : "v"(lo), "v"(hi));
        xl32[row * (X2STR / 2) + 64 + dcol] = pk;
      }
  }
  LGKM0();
  __syncthreads();

  // ---- phi GEMM1 (K=256) ----
  f32x4 acc[4][2] = {};
#pragma unroll 1
  for (int ks = 0; ks < 8; ++ks) {
    const int k0 = ks * 32;
    bf16x8 a[4], b[2];
#pragma unroll
    for (int rt = 0; rt < 4; ++rt)
      a[rt] = *reinterpret_cast<const bf16x8*>(&xl[(rt * 16 + lr) * X2STR + k0 + lk]);
#pragma unroll
    for (int ct = 0; ct < 2; ++ct)
      b[ct] = *reinterpret_cast<const bf16x8*>(&PW1T[(size_t)(n0 + ct * 16) * 256 + k0 + lk]);
#pragma unroll
    for (int rt = 0; rt < 4; ++rt)
#pragma unroll
      for (int ct = 0; ct < 2; ++ct)
        acc[rt][ct] = MFMA16(a[rt], b[ct], acc[rt][ct]);
  }

  {
    const float b1v0 = b1[n0], b1v1 = b1[n0 + 16];
#pragma unroll
    for (int rt = 0; rt < 4; ++rt)
#pragma unroll
      for (int ct = 0; ct < 2; ++ct) {
        const float bb = ct ? b1v1 : b1v0;
#pragma unroll
        for (int j = 0; j < 4; ++j) {
          float v = acc[rt][ct][j] + bb;
          v = v * __builtin_amdgcn_rcpf(1.f + __expf(-v));
          hl[(rt * 16 + rowh + j) * HSTR + n0 + ct * 16] = cvt1_pk(v);
        }
      }
  }
  __syncthreads();

  // ---- phi GEMM2 ----
  f32x4 acc2[4][2] = {};
#pragma unroll
  for (int ks = 0; ks < 4; ++ks) {
    const int k0 = ks * 32;
    bf16x8 a[4], b[2];
#pragma unroll
    for (int rt = 0; rt < 4; ++rt)
      a[rt] = *reinterpret_cast<const bf16x8*>(&hl[(rt * 16 + lr) * HSTR + k0 + lk]);
#pragma unroll
    for (int ct = 0; ct < 2; ++ct)
      b[ct] = *reinterpret_cast<const bf16x8*>(&PW2T[(size_t)(n0 + ct * 16) * 128 + k0 + lk]);
#pragma unroll
    for (int rt = 0; rt < 4; ++rt)
#pragma unroll
      for (int ct = 0; ct < 2; ++ct)
        acc2[rt][ct] = MFMA16(a[rt], b[ct], acc2[rt][ct]);
  }

  {
    const float b2v0 = b2[n0], b2v1 = b2[n0 + 16];
#pragma unroll
    for (int rt = 0; rt < 4; ++rt)
#pragma unroll
      for (int j = 0; j < 4; ++j) {
        const int row = rt * 16 + rowh + j;
        const int r = r0 + row;
        if (r < NP) {
          out[(size_t)r * 128 + n0]      = h_pair[(size_t)r * 128 + n0]      + acc2[rt][0][j] + b2v0;
          out[(size_t)r * 128 + n0 + 16] = h_pair[(size_t)r * 128 + n0 + 16] + acc2[rt][1][j] + b2v1;
        }
      }
  }
}

// ===================== R0 fallback (tiny ws) =====================
#define PSI_W1T_OFF 0
#define PSI_W2T_OFF 53248
#define PHI_W1T_OFF 69632
#define PHI_W2T_OFF 102400
#define WS_U16_TOTAL 118784
#define XSTR 424

__global__ void k_prep(const float* __restrict__ psi_w1, const float* __restrict__ psi_w2,
                       const float* __restrict__ phi_w1, const float* __restrict__ phi_w2,
                       u16* __restrict__ ws) {
  int i = blockIdx.x * 256 + threadIdx.x;
  if (i < 128 * 416) {
    int n = i / 416, k = i % 416;
    ws[PSI_W1T_OFF + i] = f2bf(k < 388 ? psi_w1[k * 128 + n] : 0.f);
    return;
  }
  i -= 128 * 416;
  if (i < 128 * 128) {
    int n = i / 128, k = i % 128;
    ws[PSI_W2T_OFF + i] = f2bf(psi_w2[k * 128 + n]);
    return;
  }
  i -= 128 * 128;
  if (i < 128 * 256) {
    int n = i / 256, k = i % 256;
    ws[PHI_W1T_OFF + i] = f2bf(phi_w1[k * 128 + n]);
    return;
  }
  i -= 128 * 256;
  if (i < 128 * 128) {
    int n = i / 128, k = i % 128;
    ws[PHI_W2T_OFF + i] = f2bf(phi_w2[k * 128 + n]);
  }
}

__global__ __launch_bounds__(256, 2) void k_triplet(
    const float* __restrict__ h_pair,
    const int* __restrict__ ivu, const int* __restrict__ iuw, const int* __restrict__ ivw,
    const float* __restrict__ geom,
    const u16* __restrict__ W1T, const u16* __restrict__ W2T,
    const float* __restrict__ b1, const float* __restrict__ b2,
    float* __restrict__ agg) {
  __shared__ __align__(16) u16 xl[64 * XSTR];
  __shared__ __align__(16) u16 hl[64 * HSTR];
  __shared__ int svw[64];

  const int tid = threadIdx.x;
  const int t0 = blockIdx.x * 64;

  {
    const int row = tid >> 2, q = tid & 3;
    const int t = t0 + row;
    const int tc = (t < T_TRIP) ? t : (T_TRIP - 1);
    if (q == 0) svw[row] = (t < T_TRIP) ? ivw[tc] : -1;
    int idx[3];
    idx[0] = ivu[tc]; idx[1] = iuw[tc]; idx[2] = ivw[tc];
#pragma unroll
    for (int s = 0; s < 3; ++s) {
      const float4* src = reinterpret_cast<const float4*>(h_pair + (size_t)idx[s] * 128 + q * 32);
      u16* dst = &xl[row * XSTR + s * 128 + q * 32];
#pragma unroll
      for (int i = 0; i < 8; ++i)
        *reinterpret_cast<ushort4*>(dst + i * 4) = cvt4(src[i]);
    }
  }
  if (tid < 64) {
    const int t = t0 + tid;
    const int tc = (t < T_TRIP) ? t : (T_TRIP - 1);
    const float4 g = reinterpret_cast<const float4*>(geom)[tc];
    u16* dst = &xl[tid * XSTR + 384];
    *reinterpret_cast<ushort4*>(dst) = cvt4(g);
    ushort4 z = {0, 0, 0, 0};
#pragma unroll
    for (int i = 1; i < 8; ++i) *reinterpret_cast<ushort4*>(dst + i * 4) = z;
  }
  __syncthreads();

  const int w = tid >> 6;
  const int l = tid & 63;
  const int lr = l & 15;
  const int lk = (l >> 4) << 3;
  const int n0 = w * 32 + lr;
  const int rowh = (l >> 4) << 2;

  f32x4 acc[4][2] = {};
#pragma unroll 1
  for (int ks = 0; ks < 13; ++ks) {
    const int k0 = ks * 32;
    bf16x8 a[4], b[2];
#pragma unroll
    for (int rt = 0; rt < 4; ++rt)
      a[rt] = *reinterpret_cast<const bf16x8*>(&xl[(rt * 16 + lr) * XSTR + k0 + lk]);
#pragma unroll
    for (int ct = 0; ct < 2; ++ct)
      b[ct] = *reinterpret_cast<const bf16x8*>(&W1T[(size_t)(n0 + ct * 16) * 416 + k0 + lk]);
#pragma unroll
    for (int rt = 0; rt < 4; ++rt)
#pragma unroll
      for (int ct = 0; ct < 2; ++ct)
        acc[rt][ct] = MFMA16(a[rt], b[ct], acc[rt][ct]);
  }

  {
    const float b1v0 = b1[n0], b1v1 = b1[n0 + 16];
#pragma unroll
    for (int rt = 0; rt < 4; ++rt)
#pragma unroll
      for (int ct = 0; ct < 2; ++ct) {
        const float bb = ct ? b1v1 : b1v0;
#pragma unroll
        for (int j = 0; j < 4; ++j) {
          float v = acc[rt][ct][j] + bb;
          v = v / (1.f + __expf(-v));
          hl[(rt * 16 + rowh + j) * HSTR + n0 + ct * 16] = f2bf(v);
        }
      }
  }
  __syncthreads();

  f32x4 acc2[4][2] = {};
#pragma unroll
  for (int ks = 0; ks < 4; ++ks) {
    const int k0 = ks * 32;
    bf16x8 a[4], b[2];
#pragma unroll
    for (int rt = 0; rt < 4; ++rt)
      a[rt] = *reinterpret_cast<const bf16x8*>(&hl[(rt * 16 + lr) * HSTR + k0 + lk]);
#pragma unroll
    for (int ct = 0; ct < 2; ++ct)
      b[ct] = *reinterpret_cast<const bf16x8*>(&W2T[(size_t)(n0 + ct * 16) * 128 + k0 + lk]);
#pragma unroll
    for (int rt = 0; rt < 4; ++rt)
#pragma unroll
      for (int ct = 0; ct < 2; ++ct)
        acc2[rt][ct] = MFMA16(a[rt], b[ct], acc2[rt][ct]);
  }

  {
    const float b2v0 = b2[n0], b2v1 = b2[n0 + 16];
#pragma unroll
    for (int rt = 0; rt < 4; ++rt)
#pragma unroll
      for (int j = 0; j < 4; ++j) {
        const int row = rt * 16 + rowh + j;
        const int dst = svw[row];
        if (dst >= 0) {
          unsafeAtomicAdd(&agg[(size_t)dst * 128 + n0], acc2[rt][0][j] + b2v0);
          unsafeAtomicAdd(&agg[(size_t)dst * 128 + n0 + 16], acc2[rt][1][j] + b2v1);
        }
      }
  }
}

__global__ __launch_bounds__(256, 2) void k_pair(
    const float* __restrict__ h_pair,
    const u16* __restrict__ W1T, const u16* __restrict__ W2T,
    const float* __restrict__ b1, const float* __restrict__ b2,
    float* __restrict__ out) {
  __shared__ __align__(16) u16 xl[64 * X2STR];
  __shared__ __align__(16) u16 hl[64 * HSTR];

  const int tid = threadIdx.x;
  const int r0 = blockIdx.x * 64;

  {
    const int row = tid >> 2, q = tid & 3;
    const int r = r0 + row;
    const int rc = (r < NP) ? r : (NP - 1);
    const float4* s1 = reinterpret_cast<const float4*>(h_pair + (size_t)rc * 128 + q * 32);
    const float4* s2 = reinterpret_cast<const float4*>(out + (size_t)rc * 128 + q * 32);
    u16* d1 = &xl[row * X2STR + q * 32];
    u16* d2 = &xl[row * X2STR + 128 + q * 32];
#pragma unroll
    for (int i = 0; i < 8; ++i) {
      *reinterpret_cast<ushort4*>(d1 + i * 4) = cvt4(s1[i]);
      *reinterpret_cast<ushort4*>(d2 + i * 4) = cvt4(s2[i]);
    }
  }
  __syncthreads();

  const int w = tid >> 6;
  const int l = tid & 63;
  const int lr = l & 15;
  const int lk = (l >> 4) << 3;
  const int n0 = w * 32 + lr;
  const int rowh = (l >> 4) << 2;

  f32x4 acc[4][2] = {};
#pragma unroll 1
  for (int ks = 0; ks < 8; ++ks) {
    const int k0 = ks * 32;
    bf16x8 a[4], b[2];
#pragma unroll
    for (int rt = 0; rt < 4; ++rt)
      a[rt] = *reinterpret_cast<const bf16x8*>(&xl[(rt * 16 + lr) * X2STR + k0 + lk]);
#pragma unroll
    for (int ct = 0; ct < 2; ++ct)
      b[ct] = *reinterpret_cast<const bf16x8*>(&W1T[(size_t)(n0 + ct * 16) * 256 + k0 + lk]);
#pragma unroll
    for (int rt = 0; rt < 4; ++rt)
#pragma unroll
      for (int ct = 0; ct < 2; ++ct)
        acc[rt][ct] = MFMA16(a[rt], b[ct], acc[rt][ct]);
  }

  {
    const float b1v0 = b1[n0], b1v1 = b1[n0 + 16];
#pragma unroll
    for (int rt = 0; rt < 4; ++rt)
#pragma unroll
      for (int ct = 0; ct < 2; ++ct) {
        const float bb = ct ? b1v1 : b1v0;
#pragma unroll
        for (int j = 0; j < 4; ++j) {
          float v = acc[rt][ct][j] + bb;
          v = v / (1.f + __expf(-v));
          hl[(rt * 16 + rowh + j) * HSTR + n0 + ct * 16] = f2bf(v);
        }
      }
  }
  __syncthreads();

  f32x4 acc2[4][2] = {};
#pragma unroll
  for (int ks = 0; ks < 4; ++ks) {
    const int k0 = ks * 32;
    bf16x8 a[4], b[2];
#pragma unroll
    for (int rt = 0; rt < 4; ++rt)
      a[rt] = *reinterpret_cast<const bf16x8*>(&hl[(rt * 16 + lr) * HSTR + k0 + lk]);
#pragma unroll
    for (int ct = 0; ct < 2; ++ct)
      b[ct] = *reinterpret_cast<const bf16x8*>(&W2T[(size_t)(n0 + ct * 16) * 128 + k0 + lk]);
#pragma unroll
    for (int rt = 0; rt < 4; ++rt)
#pragma unroll
      for (int ct = 0; ct < 2; ++ct)
        acc2[rt][ct] = MFMA16(a[rt], b[ct], acc2[rt][ct]);
  }

  {
    const float b2v0 = b2[n0], b2v1 = b2[n0 + 16];
#pragma unroll
    for (int rt = 0; rt < 4; ++rt)
#pragma unroll
      for (int j = 0; j < 4; ++j) {
        const int row = rt * 16 + rowh + j;
        const int r = r0 + row;
        if (r < NP) {
          out[(size_t)r * 128 + n0]      = h_pair[(size_t)r * 128 + n0]      + acc2[rt][0][j] + b2v0;
          out[(size_t)r * 128 + n0 + 16] = h_pair[(size_t)r * 128 + n0 + 16] + acc2[rt][1][j] + b2v1;
        }
      }
  }
}

extern "C" void kernel_launch(void* const* d_in, const int* in_sizes, int n_in,
                              void* d_out, int out_size, void* d_ws, size_t ws_size,
                              hipStream_t stream) {
  const float* h_pair = (const float*)d_in[0];
  const int* ivu = (const int*)d_in[1];
  const int* iuw = (const int*)d_in[2];
  const int* ivw = (const int*)d_in[3];
  const float* geom = (const float*)d_in[4];
  const float* psi_w1 = (const float*)d_in[5];
  const float* psi_b1 = (const float*)d_in[6];
  const float* psi_w2 = (const float*)d_in[7];
  const float* psi_b2 = (const float*)d_in[8];
  const float* phi_w1 = (const float*)d_in[9];
  const float* phi_b1 = (const float*)d_in[10];
  const float* phi_w2 = (const float*)d_in[11];
  const float* phi_b2 = (const float*)d_in[12];

  float* out = (float*)d_out;
  u16* ws = (u16*)d_ws;
  char* wsb = (char*)d_ws;

  if (ws_size >= WS_S3) {
    int*  cnt    = (int*)(wsb + SB_CNT2);
    int*  cursor = (int*)(wsb + SB_CURSOR2);
    int*  bsum   = (int*)(wsb + SB_BSUM2);
    int4* trip   = (int4*)(wsb + SB_TRIP);
    u32*  YA     = (u32*)(wsb + SB_YA);
    u32*  YB     = (u32*)(wsb + SB_YB);
    u32*  YC     = (u32*)(wsb + SB_YC);

    hipMemsetAsync(cnt, 0, NP * sizeof(int), stream);
    k_pre3<<<5529, 256, 0, stream>>>(psi_w1, psi_w2, phi_w1, phi_w2, ivw, ws, cnt);
    k_scan1<<<98, 1024, 0, stream>>>(cnt, cursor, bsum);
    k_scan2<<<1, 128, 0, stream>>>(bsum);
    k_perm_pack<<<1954, 256, 0, stream>>>(ivu, iuw, ivw, geom, cursor, bsum, trip);
    k_proj<<<1563, 256, 0, stream>>>(h_pair, ws + FP_W1A, ws + FP_W1B, ws + FP_W1C,
                                     YA, YB, YC);
    k_gsilu2<<<(NBATCH + 3) / 4, 256, 0, stream>>>(
        YA, YB, YC, (const u32*)trip,
        reinterpret_cast<const float*>(ws + FP_W1D), psi_b1, ws + FP_AGG);
    k_pair2<<<1563, 256, 0, stream>>>(
        h_pair, ws + FP_AGG, cnt, ws + FP_W2,
        ws + FP_PW1, ws + FP_PW2, psi_b2, phi_b1, phi_b2, out);
  } else {
    hipMemsetAsync(d_out, 0, (size_t)out_size * sizeof(float), stream);
    k_prep<<<(WS_U16_TOTAL + 255) / 256, 256, 0, stream>>>(psi_w1, psi_w2, phi_w1, phi_w2, ws);
    k_triplet<<<(T_TRIP + 63) / 64, 256, 0, stream>>>(
        h_pair, ivu, iuw, ivw, geom,
        ws + PSI_W1T_OFF, ws + PSI_W2T_OFF, psi_b1, psi_b2, out);
    k_pair<<<(NP + 63) / 64, 256, 0, stream>>>(
        h_pair, ws + PHI_W1T_OFF, ws + PHI_W2T_OFF, phi_b1, phi_b2, out);
  }
}